// Round 1
// baseline (935.225 us; speedup 1.0000x reference)
//
#include <hip/hip_runtime.h>
#include <math.h>

// Problem constants (B,C,H,W)=(8,512,32,32), L=1024, 32 groups, 8 heads, ch=64
#define BATCH   8
#define CCH     512
#define LL      1024
#define NGROUPS 32
#define CPG     16      // channels per group
#define NHEADS  8
#define CHD     64      // head dim
#define BHEADS  64      // BATCH*NHEADS
#define EPSV    1e-5f

// ---------------------------------------------------------------------------
// Kernel 1: GroupNorm(32).  One block per (b, group): 16*1024 = 16384 floats,
// contiguous in memory.  float4 loads, shuffle + LDS reduce, normalize+affine.
// ---------------------------------------------------------------------------
__global__ __launch_bounds__(256) void gn_kernel(const float* __restrict__ x,
                                                 const float* __restrict__ gsc,
                                                 const float* __restrict__ gbi,
                                                 float* __restrict__ xn) {
  int bg = blockIdx.x;                 // 0..255
  int b = bg >> 5, g = bg & 31;
  size_t base = ((size_t)(b * CCH + g * CPG)) * LL;
  const float4* x4 = (const float4*)(x + base);
  float4* o4 = (float4*)(xn + base);
  int tid = threadIdx.x;

  float s = 0.f, ss = 0.f;
  float4 v[16];
#pragma unroll
  for (int it = 0; it < 16; ++it) {
    float4 f = x4[it * 256 + tid];
    v[it] = f;
    s += f.x + f.y + f.z + f.w;
    ss += f.x * f.x + f.y * f.y + f.z * f.z + f.w * f.w;
  }
#pragma unroll
  for (int m = 1; m < 64; m <<= 1) {
    s += __shfl_xor(s, m, 64);
    ss += __shfl_xor(ss, m, 64);
  }
  __shared__ float red_s[4], red_ss[4];
  int wv = tid >> 6, ln = tid & 63;
  if (ln == 0) { red_s[wv] = s; red_ss[wv] = ss; }
  __syncthreads();
  s  = red_s[0] + red_s[1] + red_s[2] + red_s[3];
  ss = red_ss[0] + red_ss[1] + red_ss[2] + red_ss[3];
  float mean = s * (1.f / 16384.f);
  float var  = ss * (1.f / 16384.f) - mean * mean;
  float rstd = rsqrtf(var + EPSV);

#pragma unroll
  for (int it = 0; it < 16; ++it) {
    int c = g * CPG + it;             // each 'it' stripe is exactly one channel
    float sc = gsc[c] * rstd;
    float bi = gbi[c];
    float4 f = v[it];
    float4 o;
    o.x = (f.x - mean) * sc + bi;
    o.y = (f.y - mean) * sc + bi;
    o.z = (f.z - mean) * sc + bi;
    o.w = (f.w - mean) * sc + bi;
    o4[it * 256 + tid] = o;
  }
}

// ---------------------------------------------------------------------------
// Kernel 2: qkv = qkv_w(1536x512) @ xn(b,512,1024) + qkv_b, scattered into
// q_t/k_t/v_t with layout (bh, l, ch) for coalesced attention loads.
// 64x64 output tile / block, K tiled by 64 in LDS (+1 pad), 4x4 micro-tile.
// ---------------------------------------------------------------------------
__global__ __launch_bounds__(256) void qkv_kernel(const float* __restrict__ xn,
                                                  const float* __restrict__ w,
                                                  const float* __restrict__ bias,
                                                  float* __restrict__ qt,
                                                  float* __restrict__ kt,
                                                  float* __restrict__ vt) {
  __shared__ float aT[64 * 65];   // [kc][o]
  __shared__ float bS[64 * 65];   // [kc][l]
  int b  = blockIdx.z;            // 0..7
  int ot = blockIdx.y;            // 0..23
  int lt = blockIdx.x;            // 0..15
  int oBase = ot * 64, lBase = lt * 64;
  int tid = threadIdx.x;
  int to = tid >> 4, tl = tid & 15;

  float acc[4][4] = {};
  for (int ct = 0; ct < 8; ++ct) {
    int cBase = ct * 64;
    __syncthreads();
#pragma unroll
    for (int it = 0; it < 16; ++it) {
      int idx = it * 256 + tid;
      int r = idx >> 6, q = idx & 63;
      aT[q * 65 + r] = w[(size_t)(oBase + r) * CCH + cBase + q];
      bS[r * 65 + q] = xn[((size_t)b * CCH + cBase + r) * LL + lBase + q];
    }
    __syncthreads();
#pragma unroll
    for (int kc = 0; kc < 64; ++kc) {
      float4 av = *(const float4*)&aT[kc * 65 + to * 4];
      float4 bv = *(const float4*)&bS[kc * 65 + tl * 4];
      float a_[4] = {av.x, av.y, av.z, av.w};
      float b_[4] = {bv.x, bv.y, bv.z, bv.w};
#pragma unroll
      for (int i = 0; i < 4; ++i)
#pragma unroll
        for (int j = 0; j < 4; ++j)
          acc[i][j] = fmaf(a_[i], b_[j], acc[i][j]);
    }
  }
  // epilogue: 4 consecutive o per thread stay within one section/head
  int o = oBase + to * 4;
  int sec = o >> 9;
  int c = o & 511;
  int head = c >> 6, ch = c & 63;
  float* dst = (sec == 0) ? qt : ((sec == 1) ? kt : vt);
  float4 bv4 = *(const float4*)&bias[o];
#pragma unroll
  for (int j = 0; j < 4; ++j) {
    int l = lBase + tl * 4 + j;
    size_t off = ((size_t)(b * NHEADS + head) * LL + l) * CHD + ch;
    float4 val;
    val.x = acc[0][j] + bv4.x;
    val.y = acc[1][j] + bv4.y;
    val.z = acc[2][j] + bv4.z;
    val.w = acc[3][j] + bv4.w;
    *(float4*)&dst[off] = val;
  }
}

// ---------------------------------------------------------------------------
// Kernel 3: flash attention.  Block = (bh, 64-row q tile).  16 k/v tiles of 64
// stream through LDS; online softmax; P goes through LDS (reusing Kt buffer)
// to re-layout for the AV product.  scale^2 = 1/8 applied to scores.
// ---------------------------------------------------------------------------
__global__ __launch_bounds__(256) void attn_kernel(const float* __restrict__ qt,
                                                   const float* __restrict__ kt,
                                                   const float* __restrict__ vt,
                                                   float* __restrict__ at) {
  __shared__ float qsT[64 * 65];  // [c][t]
  __shared__ float kp[64 * 65];   // [c][s] as Kt, reused as pbufT [s][t]
  __shared__ float vsh[64 * 65];  // [s][c]
  int bh = blockIdx.y;
  int tt = blockIdx.x;
  int tBase = tt * 64;
  int tid = threadIdx.x;
  int tr = tid >> 4, tc = tid & 15;
  int r0 = tr * 4, c0 = tc * 4;
  const float* qb = qt + (size_t)bh * LL * CHD;
  const float* kb = kt + (size_t)bh * LL * CHD;
  const float* vb = vt + (size_t)bh * LL * CHD;

#pragma unroll
  for (int it = 0; it < 16; ++it) {
    int idx = it * 256 + tid;
    int t = idx >> 6, c = idx & 63;
    qsT[c * 65 + t] = qb[(size_t)(tBase + t) * CHD + c];
  }

  float m[4], lsum[4], O[4][4];
#pragma unroll
  for (int i = 0; i < 4; ++i) {
    m[i] = -1e30f; lsum[i] = 0.f;
#pragma unroll
    for (int j = 0; j < 4; ++j) O[i][j] = 0.f;
  }

  for (int st = 0; st < 16; ++st) {
    int sBase = st * 64;
    __syncthreads();   // protect kp/vsh from previous iteration's readers
#pragma unroll
    for (int it = 0; it < 16; ++it) {
      int idx = it * 256 + tid;
      int sidx = idx >> 6, c = idx & 63;
      float kvv = kb[(size_t)(sBase + sidx) * CHD + c];
      float vvv = vb[(size_t)(sBase + sidx) * CHD + c];
      kp[c * 65 + sidx] = kvv;
      vsh[sidx * 65 + c] = vvv;
    }
    __syncthreads();

    // scores S[i][j]: rows r0+i, score-cols c0+j
    float S[4][4] = {};
#pragma unroll
    for (int cc = 0; cc < 64; ++cc) {
      float4 qv = *(const float4*)&qsT[cc * 65 + r0];
      float4 kv = *(const float4*)&kp[cc * 65 + c0];
      float a_[4] = {qv.x, qv.y, qv.z, qv.w};
      float b_[4] = {kv.x, kv.y, kv.z, kv.w};
#pragma unroll
      for (int i = 0; i < 4; ++i)
#pragma unroll
        for (int j = 0; j < 4; ++j)
          S[i][j] = fmaf(a_[i], b_[j], S[i][j]);
    }

    float pnew[4][4];
#pragma unroll
    for (int i = 0; i < 4; ++i) {
      float rmax = -1e30f;
#pragma unroll
      for (int j = 0; j < 4; ++j) {
        S[i][j] *= 0.125f;
        rmax = fmaxf(rmax, S[i][j]);
      }
      rmax = fmaxf(rmax, __shfl_xor(rmax, 1, 64));
      rmax = fmaxf(rmax, __shfl_xor(rmax, 2, 64));
      rmax = fmaxf(rmax, __shfl_xor(rmax, 4, 64));
      rmax = fmaxf(rmax, __shfl_xor(rmax, 8, 64));
      float mnew = fmaxf(m[i], rmax);
      float alpha = __expf(m[i] - mnew);
      m[i] = mnew;
      float rs = 0.f;
#pragma unroll
      for (int j = 0; j < 4; ++j) {
        float p = __expf(S[i][j] - mnew);
        pnew[i][j] = p;
        rs += p;
      }
      rs += __shfl_xor(rs, 1, 64);
      rs += __shfl_xor(rs, 2, 64);
      rs += __shfl_xor(rs, 4, 64);
      rs += __shfl_xor(rs, 8, 64);
      lsum[i] = lsum[i] * alpha + rs;
#pragma unroll
      for (int j = 0; j < 4; ++j) O[i][j] *= alpha;
    }

    __syncthreads();   // all waves done reading kp as Kt
#pragma unroll
    for (int i = 0; i < 4; ++i)
#pragma unroll
      for (int j = 0; j < 4; ++j)
        kp[(c0 + j) * 65 + r0 + i] = pnew[i][j];   // pbufT[s][t]
    __syncthreads();

    // AV: O[i][j] += sum_s pbufT[s][r0+i] * vsh[s][c0+j]
#pragma unroll
    for (int s = 0; s < 64; ++s) {
      float4 pv = *(const float4*)&kp[s * 65 + r0];
      float4 vv = *(const float4*)&vsh[s * 65 + c0];
      float a_[4] = {pv.x, pv.y, pv.z, pv.w};
      float b_[4] = {vv.x, vv.y, vv.z, vv.w};
#pragma unroll
      for (int i = 0; i < 4; ++i)
#pragma unroll
        for (int j = 0; j < 4; ++j)
          O[i][j] = fmaf(a_[i], b_[j], O[i][j]);
    }
  }

#pragma unroll
  for (int i = 0; i < 4; ++i) {
    float inv = 1.f / lsum[i];
    size_t off = ((size_t)bh * LL + tBase + r0 + i) * CHD + c0;
    float4 val;
    val.x = O[i][0] * inv;
    val.y = O[i][1] * inv;
    val.z = O[i][2] * inv;
    val.w = O[i][3] * inv;
    *(float4*)&at[off] = val;
  }
}

// ---------------------------------------------------------------------------
// Kernel 4: out = x + proj_w(512x512) @ a + proj_b.  a is in (bh,l,ch) layout;
// K-tiles of 64 are head-aligned.  Same 4x4 micro-tile GEMM; fused residual.
// ---------------------------------------------------------------------------
__global__ __launch_bounds__(256) void proj_kernel(const float* __restrict__ at,
                                                   const float* __restrict__ w,
                                                   const float* __restrict__ bias,
                                                   const float* __restrict__ xf,
                                                   float* __restrict__ out) {
  __shared__ float wT[64 * 65];   // [kc][o]
  __shared__ float aS[64 * 65];   // [kc][l]
  int b  = blockIdx.z;            // 0..7
  int ot = blockIdx.y;            // 0..7
  int lt = blockIdx.x;            // 0..15
  int oBase = ot * 64, lBase = lt * 64;
  int tid = threadIdx.x;
  int to = tid >> 4, tl = tid & 15;

  float acc[4][4] = {};
  for (int ct = 0; ct < 8; ++ct) {   // K tile == head ct
    int cBase = ct * 64;
    __syncthreads();
#pragma unroll
    for (int it = 0; it < 16; ++it) {
      int idx = it * 256 + tid;
      int r = idx >> 6, q = idx & 63;
      wT[q * 65 + r] = w[(size_t)(oBase + r) * CCH + cBase + q];
      // a[c][l] = at[(b*8+ct)][l][kc]
      aS[q * 65 + r] = at[((size_t)(b * NHEADS + ct) * LL + lBase + r) * CHD + q];
    }
    __syncthreads();
#pragma unroll
    for (int kc = 0; kc < 64; ++kc) {
      float4 wv = *(const float4*)&wT[kc * 65 + to * 4];
      float4 av = *(const float4*)&aS[kc * 65 + tl * 4];
      float a_[4] = {wv.x, wv.y, wv.z, wv.w};
      float b_[4] = {av.x, av.y, av.z, av.w};
#pragma unroll
      for (int i = 0; i < 4; ++i)
#pragma unroll
        for (int j = 0; j < 4; ++j)
          acc[i][j] = fmaf(a_[i], b_[j], acc[i][j]);
    }
  }
#pragma unroll
  for (int i = 0; i < 4; ++i) {
    int o = oBase + to * 4 + i;
    size_t off = ((size_t)b * CCH + o) * LL + lBase + tl * 4;
    float4 r = *(const float4*)&xf[off];
    float bb = bias[o];
    float4 val;
    val.x = acc[i][0] + bb + r.x;
    val.y = acc[i][1] + bb + r.y;
    val.z = acc[i][2] + bb + r.z;
    val.w = acc[i][3] + bb + r.w;
    *(float4*)&out[off] = val;
  }
}

// ---------------------------------------------------------------------------
extern "C" void kernel_launch(void* const* d_in, const int* in_sizes, int n_in,
                              void* d_out, int out_size, void* d_ws, size_t ws_size,
                              hipStream_t stream) {
  const float* x     = (const float*)d_in[0];
  const float* gsc   = (const float*)d_in[1];
  const float* gbi   = (const float*)d_in[2];
  const float* qkvw  = (const float*)d_in[3];
  const float* qkvb  = (const float*)d_in[4];
  const float* projw = (const float*)d_in[5];
  const float* projb = (const float*)d_in[6];
  float* out = (float*)d_out;
  float* ws  = (float*)d_ws;

  const size_t NEL = (size_t)BATCH * CCH * LL;   // 4Mi floats per tensor
  float* xn = ws;
  float* qt = ws + NEL;
  float* kt = ws + 2 * NEL;
  float* vt = ws + 3 * NEL;
  float* at = ws + 4 * NEL;

  hipLaunchKernelGGL(gn_kernel, dim3(NGROUPS * BATCH), dim3(256), 0, stream,
                     x, gsc, gbi, xn);
  hipLaunchKernelGGL(qkv_kernel, dim3(16, 24, BATCH), dim3(256), 0, stream,
                     xn, qkvw, qkvb, qt, kt, vt);
  hipLaunchKernelGGL(attn_kernel, dim3(16, BHEADS), dim3(256), 0, stream,
                     qt, kt, vt, at);
  hipLaunchKernelGGL(proj_kernel, dim3(16, 8, BATCH), dim3(256), 0, stream,
                     at, projw, projb, x, out);
}

// Round 2
// 318.748 us; speedup vs baseline: 2.9341x; 2.9341x over previous
//
#include <hip/hip_runtime.h>
#include <math.h>

// (B,C,H,W)=(8,512,32,32), L=1024, 32 groups, 8 heads, ch=64
#define BATCH   8
#define CCH     512
#define LL      1024
#define NHEADS  8
#define CHD     64
#define EPSV    1e-5f

typedef __bf16 bf16_t;
typedef bf16_t bf16x8 __attribute__((ext_vector_type(8)));
typedef bf16_t bf16x4 __attribute__((ext_vector_type(4)));
typedef float  f32x4  __attribute__((ext_vector_type(4)));

__device__ __forceinline__ bf16_t f2b(float f) {
  unsigned u = __float_as_uint(f);
  u += 0x7fff + ((u >> 16) & 1);               // RNE
  return __builtin_bit_cast(bf16_t, (unsigned short)(u >> 16));
}

// ---------------------------------------------------------------------------
// K1: GroupNorm stats. One block per (b,g): 16 ch x 1024 l contiguous.
// ---------------------------------------------------------------------------
__global__ __launch_bounds__(256) void gn_stats(const float* __restrict__ x,
                                                float* __restrict__ stats) {
  int bg = blockIdx.x;                         // b*32+g; data offset bg*16384
  const float4* x4 = (const float4*)(x + (size_t)bg * 16 * LL);
  int tid = threadIdx.x;
  float s = 0.f, ss = 0.f;
#pragma unroll
  for (int it = 0; it < 16; ++it) {
    float4 f = x4[it * 256 + tid];
    s += f.x + f.y + f.z + f.w;
    ss += f.x * f.x + f.y * f.y + f.z * f.z + f.w * f.w;
  }
#pragma unroll
  for (int m = 1; m < 64; m <<= 1) { s += __shfl_xor(s, m); ss += __shfl_xor(ss, m); }
  __shared__ float rs_[4], rss[4];
  int wv = tid >> 6, ln = tid & 63;
  if (ln == 0) { rs_[wv] = s; rss[wv] = ss; }
  __syncthreads();
  if (tid == 0) {
    float S = rs_[0] + rs_[1] + rs_[2] + rs_[3];
    float SS = rss[0] + rss[1] + rss[2] + rss[3];
    float mean = S * (1.f / 16384.f);
    float var = SS * (1.f / 16384.f) - mean * mean;
    stats[bg * 2] = mean;
    stats[bg * 2 + 1] = rsqrtf(var + EPSV);
  }
}

// ---------------------------------------------------------------------------
// K2: normalize + affine + transpose: x(b,c,l) fp32 -> xnT(b,l,c) bf16.
// Block = (b, 32-c tile, 64-l tile); LDS re-tile for coalesced writes.
// ---------------------------------------------------------------------------
__global__ __launch_bounds__(256) void norm_t(const float* __restrict__ x,
                                              const float* __restrict__ stats,
                                              const float* __restrict__ gsc,
                                              const float* __restrict__ gbi,
                                              bf16_t* __restrict__ xnT) {
  __shared__ bf16_t T[64 * 40];                // [l][c], stride 40 (16B-aligned rows)
  int b = blockIdx.z, c0 = blockIdx.y * 32, l0 = blockIdx.x * 64;
  int tid = threadIdx.x;
#pragma unroll
  for (int p = 0; p < 2; ++p) {
    int idx = p * 256 + tid;
    int c = idx >> 4, l4 = idx & 15;
    int cg = c0 + c;
    float4 v = *(const float4*)(x + ((size_t)(b * CCH + cg)) * LL + l0 + l4 * 4);
    int g = cg >> 4;
    float mean = stats[(b * 32 + g) * 2];
    float rstd = stats[(b * 32 + g) * 2 + 1];
    float sc = gsc[cg] * rstd;
    float bi = gbi[cg] - mean * sc;
    T[(l4 * 4 + 0) * 40 + c] = f2b(v.x * sc + bi);
    T[(l4 * 4 + 1) * 40 + c] = f2b(v.y * sc + bi);
    T[(l4 * 4 + 2) * 40 + c] = f2b(v.z * sc + bi);
    T[(l4 * 4 + 3) * 40 + c] = f2b(v.w * sc + bi);
  }
  __syncthreads();
  int l = tid >> 2, seg = tid & 3;
  bf16x8 val = *(const bf16x8*)&T[l * 40 + seg * 8];
  *(bf16x8*)(xnT + ((size_t)b * LL + l0 + l) * CCH + c0 + seg * 8) = val;
}

// ---------------------------------------------------------------------------
// K3: fp32 -> bf16 weight convert
// ---------------------------------------------------------------------------
__global__ __launch_bounds__(256) void cvt_bf16(const float* __restrict__ src,
                                                bf16_t* __restrict__ dst, int n) {
  int i = (blockIdx.x * 256 + threadIdx.x) * 4;
  if (i < n) {
    float4 v = *(const float4*)(src + i);
    bf16x4 o = {f2b(v.x), f2b(v.y), f2b(v.z), f2b(v.w)};
    *(bf16x4*)(dst + i) = o;
  }
}

// ---------------------------------------------------------------------------
// K4: qkv GEMM (MFMA). M=1536 (o), N=1024 (l), K=512 (c), batch 8.
// A = wq bf16 [o][c] (k-contig), B = xnT [l][c] (k-contig) -> all frags are
// direct 16B global loads. Block tile 128x128, wave tile 64x64.
// Epilogue scatters q,k -> (bh,l,ch) and v -> (bh,ch,l), all bf16.
// ---------------------------------------------------------------------------
__global__ __launch_bounds__(256) void qkv_mfma(const bf16_t* __restrict__ wq,
                                                const bf16_t* __restrict__ xnT,
                                                const float* __restrict__ qkvb,
                                                bf16_t* __restrict__ qt,
                                                bf16_t* __restrict__ kt,
                                                bf16_t* __restrict__ vt) {
  int tid = threadIdx.x;
  int wave = tid >> 6, lane = tid & 63;
  int lrow = lane & 15, quad = lane >> 4;
  int wm = wave >> 1, wn = wave & 1;
  int b = blockIdx.z;
  int oW = blockIdx.y * 128 + wm * 64;
  int lW = blockIdx.x * 128 + wn * 64;
  const bf16_t* ap = wq + (size_t)(oW + lrow) * CCH + quad * 8;
  const bf16_t* bp = xnT + ((size_t)b * LL + lW + lrow) * CCH + quad * 8;

  f32x4 acc[4][4] = {};
  for (int ks = 0; ks < 16; ++ks) {
    int k0 = ks * 32;
    bf16x8 af[4], bfr[4];
#pragma unroll
    for (int m = 0; m < 4; ++m) af[m] = *(const bf16x8*)(ap + m * 16 * CCH + k0);
#pragma unroll
    for (int n = 0; n < 4; ++n) bfr[n] = *(const bf16x8*)(bp + n * 16 * CCH + k0);
#pragma unroll
    for (int m = 0; m < 4; ++m)
#pragma unroll
      for (int n = 0; n < 4; ++n)
        acc[m][n] = __builtin_amdgcn_mfma_f32_16x16x32_bf16(af[m], bfr[n], acc[m][n], 0, 0, 0);
  }

#pragma unroll
  for (int m = 0; m < 4; ++m) {
#pragma unroll
    for (int i = 0; i < 4; ++i) {
      int o = oW + m * 16 + quad * 4 + i;
      float bb = qkvb[o];
      int sec = o >> 9;
      int cc = o & 511;
      int head = cc >> 6, ch = cc & 63;
      int bh = b * NHEADS + head;
#pragma unroll
      for (int n = 0; n < 4; ++n) {
        int l = lW + n * 16 + lrow;
        float val = acc[m][n][i] + bb;
        if (sec == 0)      qt[((size_t)bh * LL + l) * CHD + ch] = f2b(val);
        else if (sec == 1) kt[((size_t)bh * LL + l) * CHD + ch] = f2b(val);
        else               vt[((size_t)bh * CHD + ch) * LL + l] = f2b(val);
      }
    }
  }
}

// ---------------------------------------------------------------------------
// K5: flash attention (MFMA). Block = (bh, 64 q-rows); wave owns 16 q-rows.
// S = Q.K^T via 2 MFMAs per 16-s subtile (direct global K frags); online
// softmax on C-layout (row = quad*4+i, col = lane&15, 16-lane shfl reduce);
// P relayout through wave-private LDS; PV with direct global V^T frags.
// ---------------------------------------------------------------------------
__global__ __launch_bounds__(256) void attn_mfma(const bf16_t* __restrict__ qt,
                                                 const bf16_t* __restrict__ kt,
                                                 const bf16_t* __restrict__ vt,
                                                 bf16_t* __restrict__ at) {
  __shared__ bf16_t pb[4][16][72];             // per-wave P tile [t][s], pad 8
  int tid = threadIdx.x, wave = tid >> 6, lane = tid & 63;
  int lrow = lane & 15, quad = lane >> 4;
  int bh = blockIdx.y;
  int tW = blockIdx.x * 64 + wave * 16;
  const bf16_t* qb = qt + (size_t)bh * LL * CHD;
  const bf16_t* kb = kt + (size_t)bh * LL * CHD;
  const bf16_t* vb = vt + (size_t)bh * CHD * LL;

  bf16x8 qf0 = *(const bf16x8*)(qb + (size_t)(tW + lrow) * CHD + quad * 8);
  bf16x8 qf1 = *(const bf16x8*)(qb + (size_t)(tW + lrow) * CHD + 32 + quad * 8);

  float mrow[4] = {-1e30f, -1e30f, -1e30f, -1e30f};
  float lsum[4] = {0.f, 0.f, 0.f, 0.f};
  f32x4 Oa[4] = {};

  for (int st = 0; st < 16; ++st) {
    int sB = st * 64;
    f32x4 S[4];
#pragma unroll
    for (int ss = 0; ss < 4; ++ss) {
      const bf16_t* kp = kb + (size_t)(sB + ss * 16 + lrow) * CHD + quad * 8;
      bf16x8 k0 = *(const bf16x8*)kp;
      bf16x8 k1 = *(const bf16x8*)(kp + 32);
      f32x4 z = {0.f, 0.f, 0.f, 0.f};
      z = __builtin_amdgcn_mfma_f32_16x16x32_bf16(qf0, k0, z, 0, 0, 0);
      S[ss] = __builtin_amdgcn_mfma_f32_16x16x32_bf16(qf1, k1, S[ss] = z, 0, 0, 0);
    }
    float p[4][4];
#pragma unroll
    for (int i = 0; i < 4; ++i) {
      float rm = fmaxf(fmaxf(S[0][i], S[1][i]), fmaxf(S[2][i], S[3][i])) * 0.125f;
      rm = fmaxf(rm, __shfl_xor(rm, 1));
      rm = fmaxf(rm, __shfl_xor(rm, 2));
      rm = fmaxf(rm, __shfl_xor(rm, 4));
      rm = fmaxf(rm, __shfl_xor(rm, 8));
      float mnew = fmaxf(mrow[i], rm);
      float alpha = __expf(mrow[i] - mnew);
      mrow[i] = mnew;
      float rs = 0.f;
#pragma unroll
      for (int ss = 0; ss < 4; ++ss) {
        float pv = __expf(S[ss][i] * 0.125f - mnew);
        p[ss][i] = pv;
        rs += pv;
      }
      rs += __shfl_xor(rs, 1);
      rs += __shfl_xor(rs, 2);
      rs += __shfl_xor(rs, 4);
      rs += __shfl_xor(rs, 8);
      lsum[i] = lsum[i] * alpha + rs;
#pragma unroll
      for (int n = 0; n < 4; ++n) Oa[n][i] *= alpha;
    }
#pragma unroll
    for (int ss = 0; ss < 4; ++ss)
#pragma unroll
      for (int i = 0; i < 4; ++i)
        pb[wave][quad * 4 + i][ss * 16 + lrow] = f2b(p[ss][i]);
    asm volatile("s_waitcnt lgkmcnt(0)" ::: "memory");   // wave-private: no barrier
    bf16x8 pf0 = *(const bf16x8*)&pb[wave][lrow][quad * 8];
    bf16x8 pf1 = *(const bf16x8*)&pb[wave][lrow][32 + quad * 8];
#pragma unroll
    for (int n = 0; n < 4; ++n) {
      const bf16_t* vp = vb + (size_t)(n * 16 + lrow) * LL + sB + quad * 8;
      bf16x8 v0 = *(const bf16x8*)vp;
      bf16x8 v1 = *(const bf16x8*)(vp + 32);
      Oa[n] = __builtin_amdgcn_mfma_f32_16x16x32_bf16(pf0, v0, Oa[n], 0, 0, 0);
      Oa[n] = __builtin_amdgcn_mfma_f32_16x16x32_bf16(pf1, v1, Oa[n], 0, 0, 0);
    }
  }

  float inv[4];
#pragma unroll
  for (int i = 0; i < 4; ++i) inv[i] = 1.f / lsum[i];
  bf16_t* ab = at + (size_t)bh * LL * CHD;
#pragma unroll
  for (int n = 0; n < 4; ++n)
#pragma unroll
    for (int i = 0; i < 4; ++i)
      ab[(size_t)(tW + quad * 4 + i) * CHD + n * 16 + lrow] = f2b(Oa[n][i] * inv[i]);
}

// ---------------------------------------------------------------------------
// K6: proj GEMM (MFMA) + bias + fp32 residual. M=512, N=1024, K=512, batch 8.
// A = wp [o][c], B = at (bh,l,ch) -> both k-contig, direct frags.
// ---------------------------------------------------------------------------
__global__ __launch_bounds__(256) void proj_mfma(const bf16_t* __restrict__ wp,
                                                 const bf16_t* __restrict__ at,
                                                 const float* __restrict__ projb,
                                                 const float* __restrict__ x,
                                                 float* __restrict__ out) {
  int tid = threadIdx.x;
  int wave = tid >> 6, lane = tid & 63;
  int lrow = lane & 15, quad = lane >> 4;
  int wm = wave >> 1, wn = wave & 1;
  int b = blockIdx.z;
  int oW = blockIdx.y * 128 + wm * 64;
  int lW = blockIdx.x * 128 + wn * 64;
  const bf16_t* ap = wp + (size_t)(oW + lrow) * CCH + quad * 8;

  f32x4 acc[4][4] = {};
  for (int ks = 0; ks < 16; ++ks) {
    int k0 = ks * 32;
    int head = ks >> 1;
    int choff = (k0 & 63) + quad * 8;
    const bf16_t* bp = at + ((size_t)(b * NHEADS + head) * LL + lW + lrow) * CHD + choff;
    bf16x8 af[4], bfr[4];
#pragma unroll
    for (int m = 0; m < 4; ++m) af[m] = *(const bf16x8*)(ap + m * 16 * CCH + k0);
#pragma unroll
    for (int n = 0; n < 4; ++n) bfr[n] = *(const bf16x8*)(bp + n * 16 * CHD);
#pragma unroll
    for (int m = 0; m < 4; ++m)
#pragma unroll
      for (int n = 0; n < 4; ++n)
        acc[m][n] = __builtin_amdgcn_mfma_f32_16x16x32_bf16(af[m], bfr[n], acc[m][n], 0, 0, 0);
  }

#pragma unroll
  for (int m = 0; m < 4; ++m) {
#pragma unroll
    for (int i = 0; i < 4; ++i) {
      int o = oW + m * 16 + quad * 4 + i;
      float bb = projb[o];
#pragma unroll
      for (int n = 0; n < 4; ++n) {
        int l = lW + n * 16 + lrow;
        size_t off = ((size_t)(b * CCH + o)) * LL + l;
        out[off] = acc[m][n][i] + bb + x[off];
      }
    }
  }
}

// ---------------------------------------------------------------------------
extern "C" void kernel_launch(void* const* d_in, const int* in_sizes, int n_in,
                              void* d_out, int out_size, void* d_ws, size_t ws_size,
                              hipStream_t stream) {
  const float* x     = (const float*)d_in[0];
  const float* gsc   = (const float*)d_in[1];
  const float* gbi   = (const float*)d_in[2];
  const float* qkvw  = (const float*)d_in[3];
  const float* qkvb  = (const float*)d_in[4];
  const float* projw = (const float*)d_in[5];
  const float* projb = (const float*)d_in[6];
  float* out = (float*)d_out;

  char* ws = (char*)d_ws;
  float*  stats = (float*)ws;                                  // 2 KB
  bf16_t* wqb   = (bf16_t*)(ws + 4096);                        // 1.5 MB
  bf16_t* wpb   = (bf16_t*)(ws + 4096 + 1572864);              // 0.5 MB
  bf16_t* xnT   = (bf16_t*)(ws + 2101248);                     // 8 MB
  bf16_t* qt    = (bf16_t*)(ws + 2101248 + 8388608);
  bf16_t* kt    = (bf16_t*)(ws + 2101248 + 2 * 8388608);
  bf16_t* vt    = (bf16_t*)(ws + 2101248 + 3 * 8388608);
  bf16_t* at    = (bf16_t*)(ws + 2101248 + 4 * 8388608);

  hipLaunchKernelGGL(cvt_bf16, dim3(768), dim3(256), 0, stream, qkvw, wqb, 1536 * 512);
  hipLaunchKernelGGL(cvt_bf16, dim3(256), dim3(256), 0, stream, projw, wpb, 512 * 512);
  hipLaunchKernelGGL(gn_stats, dim3(256), dim3(256), 0, stream, x, stats);
  hipLaunchKernelGGL(norm_t, dim3(16, 16, BATCH), dim3(256), 0, stream,
                     x, stats, gsc, gbi, xnT);
  hipLaunchKernelGGL(qkv_mfma, dim3(8, 12, BATCH), dim3(256), 0, stream,
                     wqb, xnT, qkvb, qt, kt, vt);
  hipLaunchKernelGGL(attn_mfma, dim3(16, 64), dim3(256), 0, stream, qt, kt, vt, at);
  hipLaunchKernelGGL(proj_mfma, dim3(8, 4, BATCH), dim3(256), 0, stream,
                     wpb, at, projb, x, out);
}

// Round 3
// 288.122 us; speedup vs baseline: 3.2459x; 1.1063x over previous
//
#include <hip/hip_runtime.h>
#include <math.h>

// (B,C,H,W)=(8,512,32,32), L=1024, 32 groups, 8 heads, ch=64
#define BATCH   8
#define CCH     512
#define LL      1024
#define NHEADS  8
#define CHD     64
#define EPSV    1e-5f
#define QSCALE  0.1803368801111204f   // 0.125 / ln(2): folded into q so S is in log2 units

typedef __bf16 bf16_t;
typedef bf16_t bf16x8 __attribute__((ext_vector_type(8)));
typedef bf16_t bf16x4 __attribute__((ext_vector_type(4)));
typedef float  f32x4  __attribute__((ext_vector_type(4)));

__device__ __forceinline__ bf16_t f2b(float f) {
  unsigned u = __float_as_uint(f);
  u += 0x7fff + ((u >> 16) & 1);               // RNE
  return __builtin_bit_cast(bf16_t, (unsigned short)(u >> 16));
}

// ---------------------------------------------------------------------------
// K1: GroupNorm stats. One block per (b,g): 16 ch x 1024 l contiguous.
// ---------------------------------------------------------------------------
__global__ __launch_bounds__(256) void gn_stats(const float* __restrict__ x,
                                                float* __restrict__ stats) {
  int bg = blockIdx.x;
  const float4* x4 = (const float4*)(x + (size_t)bg * 16 * LL);
  int tid = threadIdx.x;
  float s = 0.f, ss = 0.f;
#pragma unroll
  for (int it = 0; it < 16; ++it) {
    float4 f = x4[it * 256 + tid];
    s += f.x + f.y + f.z + f.w;
    ss += f.x * f.x + f.y * f.y + f.z * f.z + f.w * f.w;
  }
#pragma unroll
  for (int m = 1; m < 64; m <<= 1) { s += __shfl_xor(s, m); ss += __shfl_xor(ss, m); }
  __shared__ float rs_[4], rss[4];
  int wv = tid >> 6, ln = tid & 63;
  if (ln == 0) { rs_[wv] = s; rss[wv] = ss; }
  __syncthreads();
  if (tid == 0) {
    float S = rs_[0] + rs_[1] + rs_[2] + rs_[3];
    float SS = rss[0] + rss[1] + rss[2] + rss[3];
    float mean = S * (1.f / 16384.f);
    float var = SS * (1.f / 16384.f) - mean * mean;
    stats[bg * 2] = mean;
    stats[bg * 2 + 1] = rsqrtf(var + EPSV);
  }
}

// ---------------------------------------------------------------------------
// K2: normalize + affine + transpose: x(b,c,l) fp32 -> xnT(b,l,c) bf16.
// ---------------------------------------------------------------------------
__global__ __launch_bounds__(256) void norm_t(const float* __restrict__ x,
                                              const float* __restrict__ stats,
                                              const float* __restrict__ gsc,
                                              const float* __restrict__ gbi,
                                              bf16_t* __restrict__ xnT) {
  __shared__ bf16_t T[64 * 40];
  int b = blockIdx.z, c0 = blockIdx.y * 32, l0 = blockIdx.x * 64;
  int tid = threadIdx.x;
#pragma unroll
  for (int p = 0; p < 2; ++p) {
    int idx = p * 256 + tid;
    int c = idx >> 4, l4 = idx & 15;
    int cg = c0 + c;
    float4 v = *(const float4*)(x + ((size_t)(b * CCH + cg)) * LL + l0 + l4 * 4);
    int g = cg >> 4;
    float mean = stats[(b * 32 + g) * 2];
    float rstd = stats[(b * 32 + g) * 2 + 1];
    float sc = gsc[cg] * rstd;
    float bi = gbi[cg] - mean * sc;
    T[(l4 * 4 + 0) * 40 + c] = f2b(v.x * sc + bi);
    T[(l4 * 4 + 1) * 40 + c] = f2b(v.y * sc + bi);
    T[(l4 * 4 + 2) * 40 + c] = f2b(v.z * sc + bi);
    T[(l4 * 4 + 3) * 40 + c] = f2b(v.w * sc + bi);
  }
  __syncthreads();
  int l = tid >> 2, seg = tid & 3;
  bf16x8 val = *(const bf16x8*)&T[l * 40 + seg * 8];
  *(bf16x8*)(xnT + ((size_t)b * LL + l0 + l) * CCH + c0 + seg * 8) = val;
}

// ---------------------------------------------------------------------------
// K3: fp32 -> bf16 weight convert
// ---------------------------------------------------------------------------
__global__ __launch_bounds__(256) void cvt_bf16(const float* __restrict__ src,
                                                bf16_t* __restrict__ dst, int n) {
  int i = (blockIdx.x * 256 + threadIdx.x) * 4;
  if (i < n) {
    float4 v = *(const float4*)(src + i);
    bf16x4 o = {f2b(v.x), f2b(v.y), f2b(v.z), f2b(v.w)};
    *(bf16x4*)(dst + i) = o;
  }
}

// ---------------------------------------------------------------------------
// K4: qkv GEMM (MFMA).  Epilogue: q scaled by QSCALE (softmax in log2 units),
// k plain (bh,l,ch), v permuted (bh,ch, tile*64 + (l&15)*4 + ((l>>4)&3)) so
// attention's P-LDS layout and V frags share the same s-permutation.
// ---------------------------------------------------------------------------
__global__ __launch_bounds__(256) void qkv_mfma(const bf16_t* __restrict__ wq,
                                                const bf16_t* __restrict__ xnT,
                                                const float* __restrict__ qkvb,
                                                bf16_t* __restrict__ qt,
                                                bf16_t* __restrict__ kt,
                                                bf16_t* __restrict__ vt) {
  int tid = threadIdx.x;
  int wave = tid >> 6, lane = tid & 63;
  int lrow = lane & 15, quad = lane >> 4;
  int wm = wave >> 1, wn = wave & 1;
  int b = blockIdx.z;
  int oW = blockIdx.y * 128 + wm * 64;
  int lW = blockIdx.x * 128 + wn * 64;
  const bf16_t* ap = wq + (size_t)(oW + lrow) * CCH + quad * 8;
  const bf16_t* bp = xnT + ((size_t)b * LL + lW + lrow) * CCH + quad * 8;

  f32x4 acc[4][4] = {};
  for (int ks = 0; ks < 16; ++ks) {
    int k0 = ks * 32;
    bf16x8 af[4], bfr[4];
#pragma unroll
    for (int m = 0; m < 4; ++m) af[m] = *(const bf16x8*)(ap + m * 16 * CCH + k0);
#pragma unroll
    for (int n = 0; n < 4; ++n) bfr[n] = *(const bf16x8*)(bp + n * 16 * CCH + k0);
#pragma unroll
    for (int m = 0; m < 4; ++m)
#pragma unroll
      for (int n = 0; n < 4; ++n)
        acc[m][n] = __builtin_amdgcn_mfma_f32_16x16x32_bf16(af[m], bfr[n], acc[m][n], 0, 0, 0);
  }

#pragma unroll
  for (int m = 0; m < 4; ++m) {
#pragma unroll
    for (int i = 0; i < 4; ++i) {
      int o = oW + m * 16 + quad * 4 + i;
      float bb = qkvb[o];
      int sec = o >> 9;
      int cc = o & 511;
      int head = cc >> 6, ch = cc & 63;
      int bh = b * NHEADS + head;
#pragma unroll
      for (int n = 0; n < 4; ++n) {
        int l = lW + n * 16 + lrow;
        float val = acc[m][n][i] + bb;
        if (sec == 0) {
          qt[((size_t)bh * LL + l) * CHD + ch] = f2b(val * QSCALE);
        } else if (sec == 1) {
          kt[((size_t)bh * LL + l) * CHD + ch] = f2b(val);
        } else {
          int lp = (l & ~63) | ((l & 15) << 2) | ((l >> 4) & 3);   // s-permute
          vt[((size_t)bh * CHD + ch) * LL + lp] = f2b(val);
        }
      }
    }
  }
}

// ---------------------------------------------------------------------------
// K5: flash attention (MFMA), no-max softmax in log2 units.
// Wave owns 16 q-rows.  Per 64-s tile: QK^T (8 MFMA, K prefetched 1 tile
// ahead), exp2 (16 v_exp), v_perm pack -> 4x ds_write_b64 (s-permuted),
// 2x ds_read_b128 A-frags, PV (8 MFMA, V hoisted to loop top) + row-sum via
// ones-MFMA (2).  No shuffles, no barriers, no running max.
// ---------------------------------------------------------------------------
__global__ __launch_bounds__(256) void attn_mfma(const bf16_t* __restrict__ qt,
                                                 const bf16_t* __restrict__ kt,
                                                 const bf16_t* __restrict__ vt,
                                                 bf16_t* __restrict__ at) {
  __shared__ bf16_t pb[4 * 16 * 72];           // per-wave P tile [t][pos], stride 72
  int tid = threadIdx.x, wave = tid >> 6, lane = tid & 63;
  int lrow = lane & 15, quad = lane >> 4;
  int bh = blockIdx.y;
  int tW = blockIdx.x * 64 + wave * 16;
  const bf16_t* qb = qt + (size_t)bh * LL * CHD;
  const bf16_t* kb = kt + (size_t)bh * LL * CHD;
  const bf16_t* vb = vt + (size_t)bh * CHD * LL;
  bf16_t* pw = pb + wave * 16 * 72;

  bf16x8 qf0 = *(const bf16x8*)(qb + (size_t)(tW + lrow) * CHD + quad * 8);
  bf16x8 qf1 = *(const bf16x8*)(qb + (size_t)(tW + lrow) * CHD + 32 + quad * 8);

  bf16x8 ones;
#pragma unroll
  for (int j = 0; j < 8; ++j) ones[j] = (bf16_t)1.0f;

  f32x4 Oa[4] = {};
  f32x4 Os = {};

  // K frags for tile 0
  bf16x8 kf0[4], kf1[4];
#pragma unroll
  for (int ss = 0; ss < 4; ++ss) {
    const bf16_t* kp = kb + (size_t)(ss * 16 + lrow) * CHD + quad * 8;
    kf0[ss] = *(const bf16x8*)kp;
    kf1[ss] = *(const bf16x8*)(kp + 32);
  }

  for (int st = 0; st < 16; ++st) {
    int sB = st * 64;
    // hoist current-tile V frags (latency hides under exp/pack below)
    bf16x8 vf0[4], vf1[4];
#pragma unroll
    for (int n = 0; n < 4; ++n) {
      const bf16_t* vp = vb + (size_t)(n * 16 + lrow) * LL + sB + quad * 8;
      vf0[n] = *(const bf16x8*)vp;
      vf1[n] = *(const bf16x8*)(vp + 32);
    }

    f32x4 S[4];
#pragma unroll
    for (int ss = 0; ss < 4; ++ss) {
      f32x4 z = {0.f, 0.f, 0.f, 0.f};
      z = __builtin_amdgcn_mfma_f32_16x16x32_bf16(qf0, kf0[ss], z, 0, 0, 0);
      S[ss] = __builtin_amdgcn_mfma_f32_16x16x32_bf16(qf1, kf1[ss], z, 0, 0, 0);
    }

    // prefetch next tile's K frags
    int sBn = (st < 15) ? sB + 64 : 0;
#pragma unroll
    for (int ss = 0; ss < 4; ++ss) {
      const bf16_t* kp = kb + (size_t)(sBn + ss * 16 + lrow) * CHD + quad * 8;
      kf0[ss] = *(const bf16x8*)kp;
      kf1[ss] = *(const bf16x8*)(kp + 32);
    }

    // p = exp2(S); pack truncated bf16 pairs via v_perm; store s-permuted:
    // P(t=quad*4+i, s=ss*16+lrow) at pw[t*72 + lrow*4 + ss]
    float p[4][4];
#pragma unroll
    for (int ss = 0; ss < 4; ++ss)
#pragma unroll
      for (int i = 0; i < 4; ++i)
        p[ss][i] = __builtin_amdgcn_exp2f(S[ss][i]);
#pragma unroll
    for (int i = 0; i < 4; ++i) {
      unsigned d0 = __builtin_amdgcn_perm(__float_as_uint(p[1][i]),
                                          __float_as_uint(p[0][i]), 0x07060302u);
      unsigned d1 = __builtin_amdgcn_perm(__float_as_uint(p[3][i]),
                                          __float_as_uint(p[2][i]), 0x07060302u);
      uint2* dst = (uint2*)(pw + (quad * 4 + i) * 72 + lrow * 4);
      *dst = make_uint2(d0, d1);
    }
    asm volatile("s_waitcnt lgkmcnt(0)" ::: "memory");   // wave-private LDS: no barrier

    bf16x8 pf0 = *(const bf16x8*)(pw + lrow * 72 + quad * 8);
    bf16x8 pf1 = *(const bf16x8*)(pw + lrow * 72 + 32 + quad * 8);

#pragma unroll
    for (int n = 0; n < 4; ++n) {
      Oa[n] = __builtin_amdgcn_mfma_f32_16x16x32_bf16(pf0, vf0[n], Oa[n], 0, 0, 0);
      Oa[n] = __builtin_amdgcn_mfma_f32_16x16x32_bf16(pf1, vf1[n], Oa[n], 0, 0, 0);
    }
    Os = __builtin_amdgcn_mfma_f32_16x16x32_bf16(pf0, ones, Os, 0, 0, 0);
    Os = __builtin_amdgcn_mfma_f32_16x16x32_bf16(pf1, ones, Os, 0, 0, 0);
  }

  float inv[4];
#pragma unroll
  for (int i = 0; i < 4; ++i) inv[i] = 1.f / Os[i];
  bf16_t* ab = at + (size_t)bh * LL * CHD;
#pragma unroll
  for (int n = 0; n < 4; ++n)
#pragma unroll
    for (int i = 0; i < 4; ++i)
      ab[(size_t)(tW + quad * 4 + i) * CHD + n * 16 + lrow] = f2b(Oa[n][i] * inv[i]);
}

// ---------------------------------------------------------------------------
// K6: proj GEMM (MFMA) + bias + fp32 residual.
// ---------------------------------------------------------------------------
__global__ __launch_bounds__(256) void proj_mfma(const bf16_t* __restrict__ wp,
                                                 const bf16_t* __restrict__ at,
                                                 const float* __restrict__ projb,
                                                 const float* __restrict__ x,
                                                 float* __restrict__ out) {
  int tid = threadIdx.x;
  int wave = tid >> 6, lane = tid & 63;
  int lrow = lane & 15, quad = lane >> 4;
  int wm = wave >> 1, wn = wave & 1;
  int b = blockIdx.z;
  int oW = blockIdx.y * 128 + wm * 64;
  int lW = blockIdx.x * 128 + wn * 64;
  const bf16_t* ap = wp + (size_t)(oW + lrow) * CCH + quad * 8;

  f32x4 acc[4][4] = {};
  for (int ks = 0; ks < 16; ++ks) {
    int k0 = ks * 32;
    int head = ks >> 1;
    int choff = (k0 & 63) + quad * 8;
    const bf16_t* bp = at + ((size_t)(b * NHEADS + head) * LL + lW + lrow) * CHD + choff;
    bf16x8 af[4], bfr[4];
#pragma unroll
    for (int m = 0; m < 4; ++m) af[m] = *(const bf16x8*)(ap + m * 16 * CCH + k0);
#pragma unroll
    for (int n = 0; n < 4; ++n) bfr[n] = *(const bf16x8*)(bp + n * 16 * CHD);
#pragma unroll
    for (int m = 0; m < 4; ++m)
#pragma unroll
      for (int n = 0; n < 4; ++n)
        acc[m][n] = __builtin_amdgcn_mfma_f32_16x16x32_bf16(af[m], bfr[n], acc[m][n], 0, 0, 0);
  }

#pragma unroll
  for (int m = 0; m < 4; ++m) {
#pragma unroll
    for (int i = 0; i < 4; ++i) {
      int o = oW + m * 16 + quad * 4 + i;
      float bb = projb[o];
#pragma unroll
      for (int n = 0; n < 4; ++n) {
        int l = lW + n * 16 + lrow;
        size_t off = ((size_t)(b * CCH + o)) * LL + l;
        out[off] = acc[m][n][i] + bb + x[off];
      }
    }
  }
}

// ---------------------------------------------------------------------------
extern "C" void kernel_launch(void* const* d_in, const int* in_sizes, int n_in,
                              void* d_out, int out_size, void* d_ws, size_t ws_size,
                              hipStream_t stream) {
  const float* x     = (const float*)d_in[0];
  const float* gsc   = (const float*)d_in[1];
  const float* gbi   = (const float*)d_in[2];
  const float* qkvw  = (const float*)d_in[3];
  const float* qkvb  = (const float*)d_in[4];
  const float* projw = (const float*)d_in[5];
  const float* projb = (const float*)d_in[6];
  float* out = (float*)d_out;

  char* ws = (char*)d_ws;
  float*  stats = (float*)ws;
  bf16_t* wqb   = (bf16_t*)(ws + 4096);
  bf16_t* wpb   = (bf16_t*)(ws + 4096 + 1572864);
  bf16_t* xnT   = (bf16_t*)(ws + 2101248);
  bf16_t* qt    = (bf16_t*)(ws + 2101248 + 8388608);
  bf16_t* kt    = (bf16_t*)(ws + 2101248 + 2 * 8388608);
  bf16_t* vt    = (bf16_t*)(ws + 2101248 + 3 * 8388608);
  bf16_t* at    = (bf16_t*)(ws + 2101248 + 4 * 8388608);

  hipLaunchKernelGGL(cvt_bf16, dim3(768), dim3(256), 0, stream, qkvw, wqb, 1536 * 512);
  hipLaunchKernelGGL(cvt_bf16, dim3(256), dim3(256), 0, stream, projw, wpb, 512 * 512);
  hipLaunchKernelGGL(gn_stats, dim3(256), dim3(256), 0, stream, x, stats);
  hipLaunchKernelGGL(norm_t, dim3(16, 16, BATCH), dim3(256), 0, stream,
                     x, stats, gsc, gbi, xnT);
  hipLaunchKernelGGL(qkv_mfma, dim3(8, 12, BATCH), dim3(256), 0, stream,
                     wqb, xnT, qkvb, qt, kt, vt);
  hipLaunchKernelGGL(attn_mfma, dim3(16, 64), dim3(256), 0, stream, qt, kt, vt, at);
  hipLaunchKernelGGL(proj_mfma, dim3(8, 4, BATCH), dim3(256), 0, stream,
                     wpb, at, projb, x, out);
}

// Round 4
// 217.950 us; speedup vs baseline: 4.2910x; 1.3220x over previous
//
#include <hip/hip_runtime.h>
#include <math.h>

// (B,C,H,W)=(8,512,32,32), L=1024, 32 groups, 8 heads, ch=64
#define BATCH   8
#define CCH     512
#define LL      1024
#define NHEADS  8
#define CHD     64
#define EPSV    1e-5f
#define QSCALE  0.1803368801111204f   // 0.125 / ln(2): folded into q so S is in log2 units

typedef __bf16 bf16_t;
typedef bf16_t bf16x8 __attribute__((ext_vector_type(8)));
typedef bf16_t bf16x4 __attribute__((ext_vector_type(4)));
typedef float  f32x4  __attribute__((ext_vector_type(4)));

__device__ __forceinline__ bf16_t f2b(float f) {
  unsigned u = __float_as_uint(f);
  u += 0x7fff + ((u >> 16) & 1);               // RNE
  return __builtin_bit_cast(bf16_t, (unsigned short)(u >> 16));
}

__device__ __forceinline__ void gload_lds16(const void* g, void* l) {
  __builtin_amdgcn_global_load_lds(
      (const __attribute__((address_space(1))) void*)g,
      (__attribute__((address_space(3))) void*)l, 16, 0, 0);
}

// ---------------------------------------------------------------------------
// K1: GroupNorm stats. One block per (b,g): 16 ch x 1024 l contiguous.
// ---------------------------------------------------------------------------
__global__ __launch_bounds__(256) void gn_stats(const float* __restrict__ x,
                                                float* __restrict__ stats) {
  int bg = blockIdx.x;
  const float4* x4 = (const float4*)(x + (size_t)bg * 16 * LL);
  int tid = threadIdx.x;
  float s = 0.f, ss = 0.f;
#pragma unroll
  for (int it = 0; it < 16; ++it) {
    float4 f = x4[it * 256 + tid];
    s += f.x + f.y + f.z + f.w;
    ss += f.x * f.x + f.y * f.y + f.z * f.z + f.w * f.w;
  }
#pragma unroll
  for (int m = 1; m < 64; m <<= 1) { s += __shfl_xor(s, m); ss += __shfl_xor(ss, m); }
  __shared__ float rs_[4], rss[4];
  int wv = tid >> 6, ln = tid & 63;
  if (ln == 0) { rs_[wv] = s; rss[wv] = ss; }
  __syncthreads();
  if (tid == 0) {
    float S = rs_[0] + rs_[1] + rs_[2] + rs_[3];
    float SS = rss[0] + rss[1] + rss[2] + rss[3];
    float mean = S * (1.f / 16384.f);
    float var = SS * (1.f / 16384.f) - mean * mean;
    stats[bg * 2] = mean;
    stats[bg * 2 + 1] = rsqrtf(var + EPSV);
  }
}

// ---------------------------------------------------------------------------
// K2: normalize + affine + transpose: x(b,c,l) fp32 -> xnT(b,l,c) bf16.
// ---------------------------------------------------------------------------
__global__ __launch_bounds__(256) void norm_t(const float* __restrict__ x,
                                              const float* __restrict__ stats,
                                              const float* __restrict__ gsc,
                                              const float* __restrict__ gbi,
                                              bf16_t* __restrict__ xnT) {
  __shared__ bf16_t T[64 * 40];
  int b = blockIdx.z, c0 = blockIdx.y * 32, l0 = blockIdx.x * 64;
  int tid = threadIdx.x;
#pragma unroll
  for (int p = 0; p < 2; ++p) {
    int idx = p * 256 + tid;
    int c = idx >> 4, l4 = idx & 15;
    int cg = c0 + c;
    float4 v = *(const float4*)(x + ((size_t)(b * CCH + cg)) * LL + l0 + l4 * 4);
    int g = cg >> 4;
    float mean = stats[(b * 32 + g) * 2];
    float rstd = stats[(b * 32 + g) * 2 + 1];
    float sc = gsc[cg] * rstd;
    float bi = gbi[cg] - mean * sc;
    T[(l4 * 4 + 0) * 40 + c] = f2b(v.x * sc + bi);
    T[(l4 * 4 + 1) * 40 + c] = f2b(v.y * sc + bi);
    T[(l4 * 4 + 2) * 40 + c] = f2b(v.z * sc + bi);
    T[(l4 * 4 + 3) * 40 + c] = f2b(v.w * sc + bi);
  }
  __syncthreads();
  int l = tid >> 2, seg = tid & 3;
  bf16x8 val = *(const bf16x8*)&T[l * 40 + seg * 8];
  *(bf16x8*)(xnT + ((size_t)b * LL + l0 + l) * CCH + c0 + seg * 8) = val;
}

// ---------------------------------------------------------------------------
// K3: fp32 -> bf16 weight convert
// ---------------------------------------------------------------------------
__global__ __launch_bounds__(256) void cvt_bf16(const float* __restrict__ src,
                                                bf16_t* __restrict__ dst, int n) {
  int i = (blockIdx.x * 256 + threadIdx.x) * 4;
  if (i < n) {
    float4 v = *(const float4*)(src + i);
    bf16x4 o = {f2b(v.x), f2b(v.y), f2b(v.z), f2b(v.w)};
    *(bf16x4*)(dst + i) = o;
  }
}

// ---------------------------------------------------------------------------
// K4: qkv GEMM (MFMA).  Grid (x=b, y=ot, z=lt) so linear%8 == b -> all blocks
// sharing xnT[b] land on one XCD (L2 locality).  Epilogue: q scaled by QSCALE,
// k plain (bh,l,ch), v transposed+s-permuted (bh,ch,lp).
// ---------------------------------------------------------------------------
__global__ __launch_bounds__(256) void qkv_mfma(const bf16_t* __restrict__ wq,
                                                const bf16_t* __restrict__ xnT,
                                                const float* __restrict__ qkvb,
                                                bf16_t* __restrict__ qt,
                                                bf16_t* __restrict__ kt,
                                                bf16_t* __restrict__ vt) {
  int tid = threadIdx.x;
  int wave = tid >> 6, lane = tid & 63;
  int lrow = lane & 15, quad = lane >> 4;
  int wm = wave >> 1, wn = wave & 1;
  int b = blockIdx.x;
  int oW = blockIdx.y * 128 + wm * 64;
  int lW = blockIdx.z * 128 + wn * 64;
  const bf16_t* ap = wq + (size_t)(oW + lrow) * CCH + quad * 8;
  const bf16_t* bp = xnT + ((size_t)b * LL + lW + lrow) * CCH + quad * 8;

  f32x4 acc[4][4] = {};
  for (int ks = 0; ks < 16; ++ks) {
    int k0 = ks * 32;
    bf16x8 af[4], bfr[4];
#pragma unroll
    for (int m = 0; m < 4; ++m) af[m] = *(const bf16x8*)(ap + m * 16 * CCH + k0);
#pragma unroll
    for (int n = 0; n < 4; ++n) bfr[n] = *(const bf16x8*)(bp + n * 16 * CCH + k0);
#pragma unroll
    for (int m = 0; m < 4; ++m)
#pragma unroll
      for (int n = 0; n < 4; ++n)
        acc[m][n] = __builtin_amdgcn_mfma_f32_16x16x32_bf16(af[m], bfr[n], acc[m][n], 0, 0, 0);
  }

#pragma unroll
  for (int m = 0; m < 4; ++m) {
#pragma unroll
    for (int i = 0; i < 4; ++i) {
      int o = oW + m * 16 + quad * 4 + i;
      float bb = qkvb[o];
      int sec = o >> 9;
      int cc = o & 511;
      int head = cc >> 6, ch = cc & 63;
      int bh = b * NHEADS + head;
#pragma unroll
      for (int n = 0; n < 4; ++n) {
        int l = lW + n * 16 + lrow;
        float val = acc[m][n][i] + bb;
        if (sec == 0) {
          qt[((size_t)bh * LL + l) * CHD + ch] = f2b(val * QSCALE);
        } else if (sec == 1) {
          kt[((size_t)bh * LL + l) * CHD + ch] = f2b(val);
        } else {
          int lp = (l & ~63) | ((l & 15) << 2) | ((l >> 4) & 3);   // s-permute
          vt[((size_t)bh * CHD + ch) * LL + lp] = f2b(val);
        }
      }
    }
  }
}

// ---------------------------------------------------------------------------
// K5: flash attention (MFMA), no-max softmax in log2 units.
// Grid (x=bh, y=t-tile) -> linear%8 == bh%8: all 16 t-blocks of a bh share one
// XCD's L2 (K/V working set 2 MB/XCD).  K and V tiles staged once per block
// into double-buffered LDS via global_load_lds (width 16), XOR-granule swizzle
// applied on the GLOBAL source address so frag ds_read_b128s are conflict-free.
// Softmax: exp2 only, row-sum via ones-MFMA, P through wave-private LDS.
// ---------------------------------------------------------------------------
__global__ __launch_bounds__(256) void attn_mfma(const bf16_t* __restrict__ qt,
                                                 const bf16_t* __restrict__ kt,
                                                 const bf16_t* __restrict__ vt,
                                                 bf16_t* __restrict__ at) {
  __shared__ bf16_t kbuf[2][64 * 64];          // [s][ch], 128 B rows, granule-swizzled
  __shared__ bf16_t vbuf[2][64 * 64];          // [ch][s-permuted], same swizzle
  __shared__ bf16_t pb[4 * 16 * 72];           // per-wave P tile [t][pos], stride 72
  int tid = threadIdx.x, wave = tid >> 6, lane = tid & 63;
  int lrow = lane & 15, quad = lane >> 4;
  int bh = blockIdx.x;
  int tW = blockIdx.y * 64 + wave * 16;
  const bf16_t* qb = qt + (size_t)bh * LL * CHD;
  const bf16_t* kb = kt + (size_t)bh * LL * CHD;
  const bf16_t* vb = vt + (size_t)bh * CHD * LL;
  bf16_t* pw = pb + wave * 16 * 72;

  // staging geometry: chunk c = 1024 B = 8 rows of 128 B; lane covers
  // row (c*8 + lane/8), swizzled granule ((lane&7) ^ (lane/8)) * 16 B.
  int srow = lane >> 3;
  int sgb = (((lane & 7) ^ srow) << 4);

  bf16x8 qf0 = *(const bf16x8*)(qb + (size_t)(tW + lrow) * CHD + quad * 8);
  bf16x8 qf1 = *(const bf16x8*)(qb + (size_t)(tW + lrow) * CHD + 32 + quad * 8);

  bf16x8 ones;
#pragma unroll
  for (int j = 0; j < 8; ++j) ones[j] = (bf16_t)1.0f;

  f32x4 Oa[4] = {};
  f32x4 Os = {};

  // stage tile 0 into buffer 0
#pragma unroll
  for (int j = 0; j < 2; ++j) {
    int c = wave * 2 + j;
    int R = c * 8 + srow;
    gload_lds16((const char*)(kb + (size_t)R * CHD) + sgb, (char*)&kbuf[0][0] + c * 1024);
    gload_lds16((const char*)(vb + (size_t)R * LL) + sgb, (char*)&vbuf[0][0] + c * 1024);
  }
  __syncthreads();

  int swz0 = (quad ^ (lrow & 7)) * 8;          // element offset of granule quad
  int swz1 = ((quad + 4) ^ (lrow & 7)) * 8;    // element offset of granule quad+4

  for (int st = 0; st < 16; ++st) {
    int cur = st & 1;
    if (st < 15) {                              // stage next tile into other buffer
      int sBn = (st + 1) * 64;
#pragma unroll
      for (int j = 0; j < 2; ++j) {
        int c = wave * 2 + j;
        int R = c * 8 + srow;
        gload_lds16((const char*)(kb + (size_t)(sBn + R) * CHD) + sgb,
                    (char*)&kbuf[cur ^ 1][0] + c * 1024);
        gload_lds16((const char*)(vb + (size_t)R * LL + sBn) + sgb,
                    (char*)&vbuf[cur ^ 1][0] + c * 1024);
      }
    }
    const bf16_t* kbase = &kbuf[cur][0];
    const bf16_t* vbase = &vbuf[cur][0];

    f32x4 S[4];
#pragma unroll
    for (int ss = 0; ss < 4; ++ss) {
      int s = ss * 16 + lrow;
      bf16x8 k0 = *(const bf16x8*)(kbase + s * 64 + swz0);
      bf16x8 k1 = *(const bf16x8*)(kbase + s * 64 + swz1);
      f32x4 z = {0.f, 0.f, 0.f, 0.f};
      z = __builtin_amdgcn_mfma_f32_16x16x32_bf16(qf0, k0, z, 0, 0, 0);
      S[ss] = __builtin_amdgcn_mfma_f32_16x16x32_bf16(qf1, k1, z, 0, 0, 0);
    }

    // p = exp2(S); pack truncated bf16 pairs; store s-permuted to wave-private LDS
    float p[4][4];
#pragma unroll
    for (int ss = 0; ss < 4; ++ss)
#pragma unroll
      for (int i = 0; i < 4; ++i)
        p[ss][i] = __builtin_amdgcn_exp2f(S[ss][i]);
#pragma unroll
    for (int i = 0; i < 4; ++i) {
      unsigned d0 = __builtin_amdgcn_perm(__float_as_uint(p[1][i]),
                                          __float_as_uint(p[0][i]), 0x07060302u);
      unsigned d1 = __builtin_amdgcn_perm(__float_as_uint(p[3][i]),
                                          __float_as_uint(p[2][i]), 0x07060302u);
      uint2* dst = (uint2*)(pw + (quad * 4 + i) * 72 + lrow * 4);
      *dst = make_uint2(d0, d1);
    }
    asm volatile("s_waitcnt lgkmcnt(0)" ::: "memory");   // wave-private P: no barrier

    bf16x8 pf0 = *(const bf16x8*)(pw + lrow * 72 + quad * 8);
    bf16x8 pf1 = *(const bf16x8*)(pw + lrow * 72 + 32 + quad * 8);

#pragma unroll
    for (int n = 0; n < 4; ++n) {
      int r = (n * 16 + lrow) * 64;
      bf16x8 v0 = *(const bf16x8*)(vbase + r + swz0);
      bf16x8 v1 = *(const bf16x8*)(vbase + r + swz1);
      Oa[n] = __builtin_amdgcn_mfma_f32_16x16x32_bf16(pf0, v0, Oa[n], 0, 0, 0);
      Oa[n] = __builtin_amdgcn_mfma_f32_16x16x32_bf16(pf1, v1, Oa[n], 0, 0, 0);
    }
    Os = __builtin_amdgcn_mfma_f32_16x16x32_bf16(pf0, ones, Os, 0, 0, 0);
    Os = __builtin_amdgcn_mfma_f32_16x16x32_bf16(pf1, ones, Os, 0, 0, 0);

    __syncthreads();   // stage(st+1) drained; all waves done with buf[cur]
  }

  float inv[4];
#pragma unroll
  for (int i = 0; i < 4; ++i) inv[i] = 1.f / Os[i];
  bf16_t* ab = at + (size_t)bh * LL * CHD;
#pragma unroll
  for (int n = 0; n < 4; ++n)
#pragma unroll
    for (int i = 0; i < 4; ++i)
      ab[(size_t)(tW + quad * 4 + i) * CHD + n * 16 + lrow] = f2b(Oa[n][i] * inv[i]);
}

// ---------------------------------------------------------------------------
// K6: proj GEMM (MFMA) + bias + fp32 residual.  Grid (x=b, y=ot, z=lt):
// linear%8 == b for XCD locality on at[b].
// ---------------------------------------------------------------------------
__global__ __launch_bounds__(256) void proj_mfma(const bf16_t* __restrict__ wp,
                                                 const bf16_t* __restrict__ at,
                                                 const float* __restrict__ projb,
                                                 const float* __restrict__ x,
                                                 float* __restrict__ out) {
  int tid = threadIdx.x;
  int wave = tid >> 6, lane = tid & 63;
  int lrow = lane & 15, quad = lane >> 4;
  int wm = wave >> 1, wn = wave & 1;
  int b = blockIdx.x;
  int oW = blockIdx.y * 128 + wm * 64;
  int lW = blockIdx.z * 128 + wn * 64;
  const bf16_t* ap = wp + (size_t)(oW + lrow) * CCH + quad * 8;

  f32x4 acc[4][4] = {};
  for (int ks = 0; ks < 16; ++ks) {
    int k0 = ks * 32;
    int head = ks >> 1;
    int choff = (k0 & 63) + quad * 8;
    const bf16_t* bp = at + ((size_t)(b * NHEADS + head) * LL + lW + lrow) * CHD + choff;
    bf16x8 af[4], bfr[4];
#pragma unroll
    for (int m = 0; m < 4; ++m) af[m] = *(const bf16x8*)(ap + m * 16 * CCH + k0);
#pragma unroll
    for (int n = 0; n < 4; ++n) bfr[n] = *(const bf16x8*)(bp + n * 16 * CHD);
#pragma unroll
    for (int m = 0; m < 4; ++m)
#pragma unroll
      for (int n = 0; n < 4; ++n)
        acc[m][n] = __builtin_amdgcn_mfma_f32_16x16x32_bf16(af[m], bfr[n], acc[m][n], 0, 0, 0);
  }

#pragma unroll
  for (int m = 0; m < 4; ++m) {
#pragma unroll
    for (int i = 0; i < 4; ++i) {
      int o = oW + m * 16 + quad * 4 + i;
      float bb = projb[o];
#pragma unroll
      for (int n = 0; n < 4; ++n) {
        int l = lW + n * 16 + lrow;
        size_t off = ((size_t)(b * CCH + o)) * LL + l;
        out[off] = acc[m][n][i] + bb + x[off];
      }
    }
  }
}

// ---------------------------------------------------------------------------
extern "C" void kernel_launch(void* const* d_in, const int* in_sizes, int n_in,
                              void* d_out, int out_size, void* d_ws, size_t ws_size,
                              hipStream_t stream) {
  const float* x     = (const float*)d_in[0];
  const float* gsc   = (const float*)d_in[1];
  const float* gbi   = (const float*)d_in[2];
  const float* qkvw  = (const float*)d_in[3];
  const float* qkvb  = (const float*)d_in[4];
  const float* projw = (const float*)d_in[5];
  const float* projb = (const float*)d_in[6];
  float* out = (float*)d_out;

  char* ws = (char*)d_ws;
  float*  stats = (float*)ws;
  bf16_t* wqb   = (bf16_t*)(ws + 4096);
  bf16_t* wpb   = (bf16_t*)(ws + 4096 + 1572864);
  bf16_t* xnT   = (bf16_t*)(ws + 2101248);
  bf16_t* qt    = (bf16_t*)(ws + 2101248 + 8388608);
  bf16_t* kt    = (bf16_t*)(ws + 2101248 + 2 * 8388608);
  bf16_t* vt    = (bf16_t*)(ws + 2101248 + 3 * 8388608);
  bf16_t* at    = (bf16_t*)(ws + 2101248 + 4 * 8388608);

  hipLaunchKernelGGL(cvt_bf16, dim3(768), dim3(256), 0, stream, qkvw, wqb, 1536 * 512);
  hipLaunchKernelGGL(cvt_bf16, dim3(256), dim3(256), 0, stream, projw, wpb, 512 * 512);
  hipLaunchKernelGGL(gn_stats, dim3(256), dim3(256), 0, stream, x, stats);
  hipLaunchKernelGGL(norm_t, dim3(16, 16, BATCH), dim3(256), 0, stream,
                     x, stats, gsc, gbi, xnT);
  hipLaunchKernelGGL(qkv_mfma, dim3(BATCH, 12, 8), dim3(256), 0, stream,
                     wqb, xnT, qkvb, qt, kt, vt);
  hipLaunchKernelGGL(attn_mfma, dim3(64, 16), dim3(256), 0, stream, qt, kt, vt, at);
  hipLaunchKernelGGL(proj_mfma, dim3(BATCH, 4, 8), dim3(256), 0, stream,
                     wpb, at, projb, x, out);
}

// Round 5
// 172.128 us; speedup vs baseline: 5.4333x; 1.2662x over previous
//
#include <hip/hip_runtime.h>
#include <math.h>

// (B,C,H,W)=(8,512,32,32), L=1024, 32 groups, 8 heads, ch=64
#define BATCH   8
#define CCH     512
#define LL      1024
#define NHEADS  8
#define CHD     64
#define EPSV    1e-5f
#define QSCALE  0.1803368801111204f   // 0.125 / ln(2): folded into q so S is in log2 units

typedef __bf16 bf16_t;
typedef bf16_t bf16x8 __attribute__((ext_vector_type(8)));
typedef bf16_t bf16x4 __attribute__((ext_vector_type(4)));
typedef float  f32x4  __attribute__((ext_vector_type(4)));

__device__ __forceinline__ bf16_t f2b(float f) {
  unsigned u = __float_as_uint(f);
  u += 0x7fff + ((u >> 16) & 1);               // RNE
  return __builtin_bit_cast(bf16_t, (unsigned short)(u >> 16));
}

__device__ __forceinline__ unsigned pack2(float lo, float hi) {
  unsigned a = (unsigned)__builtin_bit_cast(unsigned short, f2b(lo));
  unsigned b = (unsigned)__builtin_bit_cast(unsigned short, f2b(hi));
  return (b << 16) | a;
}

__device__ __forceinline__ void gload_lds16(const void* g, void* l) {
  __builtin_amdgcn_global_load_lds(
      (const __attribute__((address_space(1))) void*)g,
      (__attribute__((address_space(3))) void*)l, 16, 0, 0);
}

// ---------------------------------------------------------------------------
// K1: GroupNorm stats. One block per (b,g): 16 ch x 1024 l contiguous.
// ---------------------------------------------------------------------------
__global__ __launch_bounds__(256) void gn_stats(const float* __restrict__ x,
                                                float* __restrict__ stats) {
  int bg = blockIdx.x;
  const float4* x4 = (const float4*)(x + (size_t)bg * 16 * LL);
  int tid = threadIdx.x;
  float s = 0.f, ss = 0.f;
#pragma unroll
  for (int it = 0; it < 16; ++it) {
    float4 f = x4[it * 256 + tid];
    s += f.x + f.y + f.z + f.w;
    ss += f.x * f.x + f.y * f.y + f.z * f.z + f.w * f.w;
  }
#pragma unroll
  for (int m = 1; m < 64; m <<= 1) { s += __shfl_xor(s, m); ss += __shfl_xor(ss, m); }
  __shared__ float rs_[4], rss[4];
  int wv = tid >> 6, ln = tid & 63;
  if (ln == 0) { rs_[wv] = s; rss[wv] = ss; }
  __syncthreads();
  if (tid == 0) {
    float S = rs_[0] + rs_[1] + rs_[2] + rs_[3];
    float SS = rss[0] + rss[1] + rss[2] + rss[3];
    float mean = S * (1.f / 16384.f);
    float var = SS * (1.f / 16384.f) - mean * mean;
    stats[bg * 2] = mean;
    stats[bg * 2 + 1] = rsqrtf(var + EPSV);
  }
}

// ---------------------------------------------------------------------------
// K2: normalize + affine + transpose: x(b,c,l) fp32 -> xnT(b,l,c) bf16.
// ---------------------------------------------------------------------------
__global__ __launch_bounds__(256) void norm_t(const float* __restrict__ x,
                                              const float* __restrict__ stats,
                                              const float* __restrict__ gsc,
                                              const float* __restrict__ gbi,
                                              bf16_t* __restrict__ xnT) {
  __shared__ bf16_t T[64 * 40];
  int b = blockIdx.z, c0 = blockIdx.y * 32, l0 = blockIdx.x * 64;
  int tid = threadIdx.x;
#pragma unroll
  for (int p = 0; p < 2; ++p) {
    int idx = p * 256 + tid;
    int c = idx >> 4, l4 = idx & 15;
    int cg = c0 + c;
    float4 v = *(const float4*)(x + ((size_t)(b * CCH + cg)) * LL + l0 + l4 * 4);
    int g = cg >> 4;
    float mean = stats[(b * 32 + g) * 2];
    float rstd = stats[(b * 32 + g) * 2 + 1];
    float sc = gsc[cg] * rstd;
    float bi = gbi[cg] - mean * sc;
    T[(l4 * 4 + 0) * 40 + c] = f2b(v.x * sc + bi);
    T[(l4 * 4 + 1) * 40 + c] = f2b(v.y * sc + bi);
    T[(l4 * 4 + 2) * 40 + c] = f2b(v.z * sc + bi);
    T[(l4 * 4 + 3) * 40 + c] = f2b(v.w * sc + bi);
  }
  __syncthreads();
  int l = tid >> 2, seg = tid & 3;
  bf16x8 val = *(const bf16x8*)&T[l * 40 + seg * 8];
  *(bf16x8*)(xnT + ((size_t)b * LL + l0 + l) * CCH + c0 + seg * 8) = val;
}

// ---------------------------------------------------------------------------
// K3: fp32 -> bf16 weight convert
// ---------------------------------------------------------------------------
__global__ __launch_bounds__(256) void cvt_bf16(const float* __restrict__ src,
                                                bf16_t* __restrict__ dst, int n) {
  int i = (blockIdx.x * 256 + threadIdx.x) * 4;
  if (i < n) {
    float4 v = *(const float4*)(src + i);
    bf16x4 o = {f2b(v.x), f2b(v.y), f2b(v.z), f2b(v.w)};
    *(bf16x4*)(dst + i) = o;
  }
}

// ---------------------------------------------------------------------------
// K4: qkv GEMM (MFMA), m97-style LDS staging.  Grid (x=b, y=ot, z=lt) so
// linear%8 == b (XCD/L2 locality on xnT[b]).  128x128 block tile, BK=64,
// single LDS buffer, global_load_lds width 16 with XOR-granule swizzle baked
// into the global source address (conflict-free ds_read_b128 frags).
// Epilogue: b64 packed stores; q scaled by QSCALE; v transposed+s-permuted.
// ---------------------------------------------------------------------------
__global__ __launch_bounds__(256) void qkv_mfma(const bf16_t* __restrict__ wq,
                                                const bf16_t* __restrict__ xnT,
                                                const float* __restrict__ qkvb,
                                                bf16_t* __restrict__ qt,
                                                bf16_t* __restrict__ kt,
                                                bf16_t* __restrict__ vt) {
  __shared__ bf16_t As[128 * 64];   // [row o][c], 128-B rows, granule-swizzled
  __shared__ bf16_t Bs[128 * 64];   // [row l][c]
  int tid = threadIdx.x;
  int wave = tid >> 6, lane = tid & 63;
  int lrow = lane & 15, quad = lane >> 4;
  int wm = wave >> 1, wn = wave & 1;
  int b = blockIdx.x;
  int oBase = blockIdx.y * 128, lBase = blockIdx.z * 128;
  int srow = lane >> 3;                         // 0..7 within 8-row chunk
  int sgOff = (((lane & 7) ^ srow) << 4);       // swizzled source granule (bytes)

  f32x4 acc[4][4] = {};
  for (int ktile = 0; ktile < 8; ++ktile) {
    int kB = ktile * 64;
    __syncthreads();                            // previous compute done
#pragma unroll
    for (int j = 0; j < 4; ++j) {
      int ci = wave * 4 + j;                    // 1 KB chunk = 8 rows
      int R = ci * 8 + srow;
      gload_lds16((const char*)(wq + (size_t)(oBase + R) * CCH + kB) + sgOff,
                  (char*)As + ci * 1024);
      gload_lds16((const char*)(xnT + ((size_t)b * LL + lBase + R) * CCH + kB) + sgOff,
                  (char*)Bs + ci * 1024);
    }
    __syncthreads();                            // vmcnt drained by barrier
#pragma unroll
    for (int kk = 0; kk < 2; ++kk) {
      bf16x8 af[4], bfr[4];
#pragma unroll
      for (int m = 0; m < 4; ++m) {
        int r = wm * 64 + m * 16 + lrow;
        int g = (kk * 4 + quad) ^ (lrow & 7);
        af[m] = *(const bf16x8*)(As + r * 64 + g * 8);
      }
#pragma unroll
      for (int n = 0; n < 4; ++n) {
        int r = wn * 64 + n * 16 + lrow;
        int g = (kk * 4 + quad) ^ (lrow & 7);
        bfr[n] = *(const bf16x8*)(Bs + r * 64 + g * 8);
      }
#pragma unroll
      for (int m = 0; m < 4; ++m)
#pragma unroll
        for (int n = 0; n < 4; ++n)
          acc[m][n] = __builtin_amdgcn_mfma_f32_16x16x32_bf16(af[m], bfr[n], acc[m][n], 0, 0, 0);
    }
  }

  int oW = oBase + wm * 64;
  int lW = lBase + wn * 64;
  int sec = oW >> 9;                            // wave-uniform
#pragma unroll
  for (int m = 0; m < 4; ++m) {
    int o4 = oW + m * 16 + quad * 4;            // 4 consecutive o
    float4 bb4 = *(const float4*)&qkvb[o4];
    int cc = o4 & 511;
    int head = cc >> 6, ch = cc & 63;
    int bh = b * NHEADS + head;
    if (sec == 0) {
#pragma unroll
      for (int n = 0; n < 4; ++n) {
        int l = lW + n * 16 + lrow;
        unsigned d0 = pack2((acc[m][n][0] + bb4.x) * QSCALE,
                            (acc[m][n][1] + bb4.y) * QSCALE);
        unsigned d1 = pack2((acc[m][n][2] + bb4.z) * QSCALE,
                            (acc[m][n][3] + bb4.w) * QSCALE);
        *(uint2*)(qt + ((size_t)bh * LL + l) * CHD + ch) = make_uint2(d0, d1);
      }
    } else if (sec == 1) {
#pragma unroll
      for (int n = 0; n < 4; ++n) {
        int l = lW + n * 16 + lrow;
        unsigned d0 = pack2(acc[m][n][0] + bb4.x, acc[m][n][1] + bb4.y);
        unsigned d1 = pack2(acc[m][n][2] + bb4.z, acc[m][n][3] + bb4.w);
        *(uint2*)(kt + ((size_t)bh * LL + l) * CHD + ch) = make_uint2(d0, d1);
      }
    } else {
      // v: lp = lW | lrow*4 | n  -> pack over n, store (bh, ch+i, lp)
      float bb[4] = {bb4.x, bb4.y, bb4.z, bb4.w};
#pragma unroll
      for (int i = 0; i < 4; ++i) {
        unsigned d0 = pack2(acc[m][0][i] + bb[i], acc[m][1][i] + bb[i]);
        unsigned d1 = pack2(acc[m][2][i] + bb[i], acc[m][3][i] + bb[i]);
        *(uint2*)(vt + ((size_t)bh * CHD + ch + i) * LL + lW + lrow * 4) =
            make_uint2(d0, d1);
      }
    }
  }
}

// ---------------------------------------------------------------------------
// K5: flash attention (MFMA), no-max softmax in log2 units.  (unchanged R4)
// Grid (x=bh, y=t-tile) -> linear%8 == bh%8 (XCD locality).  K/V double-
// buffered LDS via global_load_lds w16 + XOR-granule swizzle; exp2-only
// softmax; row-sum via ones-MFMA; P through wave-private LDS.
// ---------------------------------------------------------------------------
__global__ __launch_bounds__(256) void attn_mfma(const bf16_t* __restrict__ qt,
                                                 const bf16_t* __restrict__ kt,
                                                 const bf16_t* __restrict__ vt,
                                                 bf16_t* __restrict__ at) {
  __shared__ bf16_t kbuf[2][64 * 64];
  __shared__ bf16_t vbuf[2][64 * 64];
  __shared__ bf16_t pb[4 * 16 * 72];
  int tid = threadIdx.x, wave = tid >> 6, lane = tid & 63;
  int lrow = lane & 15, quad = lane >> 4;
  int bh = blockIdx.x;
  int tW = blockIdx.y * 64 + wave * 16;
  const bf16_t* qb = qt + (size_t)bh * LL * CHD;
  const bf16_t* kb = kt + (size_t)bh * LL * CHD;
  const bf16_t* vb = vt + (size_t)bh * CHD * LL;
  bf16_t* pw = pb + wave * 16 * 72;

  int srow = lane >> 3;
  int sgb = (((lane & 7) ^ srow) << 4);

  bf16x8 qf0 = *(const bf16x8*)(qb + (size_t)(tW + lrow) * CHD + quad * 8);
  bf16x8 qf1 = *(const bf16x8*)(qb + (size_t)(tW + lrow) * CHD + 32 + quad * 8);

  bf16x8 ones;
#pragma unroll
  for (int j = 0; j < 8; ++j) ones[j] = (bf16_t)1.0f;

  f32x4 Oa[4] = {};
  f32x4 Os = {};

#pragma unroll
  for (int j = 0; j < 2; ++j) {
    int c = wave * 2 + j;
    int R = c * 8 + srow;
    gload_lds16((const char*)(kb + (size_t)R * CHD) + sgb, (char*)&kbuf[0][0] + c * 1024);
    gload_lds16((const char*)(vb + (size_t)R * LL) + sgb, (char*)&vbuf[0][0] + c * 1024);
  }
  __syncthreads();

  int swz0 = (quad ^ (lrow & 7)) * 8;
  int swz1 = ((quad + 4) ^ (lrow & 7)) * 8;

  for (int st = 0; st < 16; ++st) {
    int cur = st & 1;
    if (st < 15) {
      int sBn = (st + 1) * 64;
#pragma unroll
      for (int j = 0; j < 2; ++j) {
        int c = wave * 2 + j;
        int R = c * 8 + srow;
        gload_lds16((const char*)(kb + (size_t)(sBn + R) * CHD) + sgb,
                    (char*)&kbuf[cur ^ 1][0] + c * 1024);
        gload_lds16((const char*)(vb + (size_t)R * LL + sBn) + sgb,
                    (char*)&vbuf[cur ^ 1][0] + c * 1024);
      }
    }
    const bf16_t* kbase = &kbuf[cur][0];
    const bf16_t* vbase = &vbuf[cur][0];

    f32x4 S[4];
#pragma unroll
    for (int ss = 0; ss < 4; ++ss) {
      int s = ss * 16 + lrow;
      bf16x8 k0 = *(const bf16x8*)(kbase + s * 64 + swz0);
      bf16x8 k1 = *(const bf16x8*)(kbase + s * 64 + swz1);
      f32x4 z = {0.f, 0.f, 0.f, 0.f};
      z = __builtin_amdgcn_mfma_f32_16x16x32_bf16(qf0, k0, z, 0, 0, 0);
      S[ss] = __builtin_amdgcn_mfma_f32_16x16x32_bf16(qf1, k1, z, 0, 0, 0);
    }

    float p[4][4];
#pragma unroll
    for (int ss = 0; ss < 4; ++ss)
#pragma unroll
      for (int i = 0; i < 4; ++i)
        p[ss][i] = __builtin_amdgcn_exp2f(S[ss][i]);
#pragma unroll
    for (int i = 0; i < 4; ++i) {
      unsigned d0 = __builtin_amdgcn_perm(__float_as_uint(p[1][i]),
                                          __float_as_uint(p[0][i]), 0x07060302u);
      unsigned d1 = __builtin_amdgcn_perm(__float_as_uint(p[3][i]),
                                          __float_as_uint(p[2][i]), 0x07060302u);
      uint2* dst = (uint2*)(pw + (quad * 4 + i) * 72 + lrow * 4);
      *dst = make_uint2(d0, d1);
    }
    asm volatile("s_waitcnt lgkmcnt(0)" ::: "memory");

    bf16x8 pf0 = *(const bf16x8*)(pw + lrow * 72 + quad * 8);
    bf16x8 pf1 = *(const bf16x8*)(pw + lrow * 72 + 32 + quad * 8);

#pragma unroll
    for (int n = 0; n < 4; ++n) {
      int r = (n * 16 + lrow) * 64;
      bf16x8 v0 = *(const bf16x8*)(vbase + r + swz0);
      bf16x8 v1 = *(const bf16x8*)(vbase + r + swz1);
      Oa[n] = __builtin_amdgcn_mfma_f32_16x16x32_bf16(pf0, v0, Oa[n], 0, 0, 0);
      Oa[n] = __builtin_amdgcn_mfma_f32_16x16x32_bf16(pf1, v1, Oa[n], 0, 0, 0);
    }
    Os = __builtin_amdgcn_mfma_f32_16x16x32_bf16(pf0, ones, Os, 0, 0, 0);
    Os = __builtin_amdgcn_mfma_f32_16x16x32_bf16(pf1, ones, Os, 0, 0, 0);

    __syncthreads();
  }

  float inv[4];
#pragma unroll
  for (int i = 0; i < 4; ++i) inv[i] = 1.f / Os[i];
  bf16_t* ab = at + (size_t)bh * LL * CHD;
#pragma unroll
  for (int n = 0; n < 4; ++n)
#pragma unroll
    for (int i = 0; i < 4; ++i)
      ab[(size_t)(tW + quad * 4 + i) * CHD + n * 16 + lrow] = f2b(Oa[n][i] * inv[i]);
}

// ---------------------------------------------------------------------------
// K6: proj GEMM (MFMA) + bias + fp32 residual, LDS-staged like K4.
// BK=64 == one head of at.  Grid (x=b, y=ot, z=lt), linear%8 == b.
// ---------------------------------------------------------------------------
__global__ __launch_bounds__(256) void proj_mfma(const bf16_t* __restrict__ wp,
                                                 const bf16_t* __restrict__ at,
                                                 const float* __restrict__ projb,
                                                 const float* __restrict__ x,
                                                 float* __restrict__ out) {
  __shared__ bf16_t As[128 * 64];
  __shared__ bf16_t Bs[128 * 64];
  int tid = threadIdx.x;
  int wave = tid >> 6, lane = tid & 63;
  int lrow = lane & 15, quad = lane >> 4;
  int wm = wave >> 1, wn = wave & 1;
  int b = blockIdx.x;
  int oBase = blockIdx.y * 128, lBase = blockIdx.z * 128;
  int srow = lane >> 3;
  int sgOff = (((lane & 7) ^ srow) << 4);

  f32x4 acc[4][4] = {};
  for (int ktile = 0; ktile < 8; ++ktile) {     // head = ktile
    int kB = ktile * 64;
    __syncthreads();
#pragma unroll
    for (int j = 0; j < 4; ++j) {
      int ci = wave * 4 + j;
      int R = ci * 8 + srow;
      gload_lds16((const char*)(wp + (size_t)(oBase + R) * CCH + kB) + sgOff,
                  (char*)As + ci * 1024);
      gload_lds16((const char*)(at + ((size_t)(b * NHEADS + ktile) * LL + lBase + R) * CHD) + sgOff,
                  (char*)Bs + ci * 1024);
    }
    __syncthreads();
#pragma unroll
    for (int kk = 0; kk < 2; ++kk) {
      bf16x8 af[4], bfr[4];
#pragma unroll
      for (int m = 0; m < 4; ++m) {
        int r = wm * 64 + m * 16 + lrow;
        int g = (kk * 4 + quad) ^ (lrow & 7);
        af[m] = *(const bf16x8*)(As + r * 64 + g * 8);
      }
#pragma unroll
      for (int n = 0; n < 4; ++n) {
        int r = wn * 64 + n * 16 + lrow;
        int g = (kk * 4 + quad) ^ (lrow & 7);
        bfr[n] = *(const bf16x8*)(Bs + r * 64 + g * 8);
      }
#pragma unroll
      for (int m = 0; m < 4; ++m)
#pragma unroll
        for (int n = 0; n < 4; ++n)
          acc[m][n] = __builtin_amdgcn_mfma_f32_16x16x32_bf16(af[m], bfr[n], acc[m][n], 0, 0, 0);
    }
  }

  int oW = oBase + wm * 64;
  int lW = lBase + wn * 64;
#pragma unroll
  for (int m = 0; m < 4; ++m) {
#pragma unroll
    for (int i = 0; i < 4; ++i) {
      int o = oW + m * 16 + quad * 4 + i;
      float bb = projb[o];
#pragma unroll
      for (int n = 0; n < 4; ++n) {
        int l = lW + n * 16 + lrow;
        size_t off = ((size_t)(b * CCH + o)) * LL + l;
        out[off] = acc[m][n][i] + bb + x[off];
      }
    }
  }
}

// ---------------------------------------------------------------------------
extern "C" void kernel_launch(void* const* d_in, const int* in_sizes, int n_in,
                              void* d_out, int out_size, void* d_ws, size_t ws_size,
                              hipStream_t stream) {
  const float* x     = (const float*)d_in[0];
  const float* gsc   = (const float*)d_in[1];
  const float* gbi   = (const float*)d_in[2];
  const float* qkvw  = (const float*)d_in[3];
  const float* qkvb  = (const float*)d_in[4];
  const float* projw = (const float*)d_in[5];
  const float* projb = (const float*)d_in[6];
  float* out = (float*)d_out;

  char* ws = (char*)d_ws;
  float*  stats = (float*)ws;
  bf16_t* wqb   = (bf16_t*)(ws + 4096);
  bf16_t* wpb   = (bf16_t*)(ws + 4096 + 1572864);
  bf16_t* xnT   = (bf16_t*)(ws + 2101248);
  bf16_t* qt    = (bf16_t*)(ws + 2101248 + 8388608);
  bf16_t* kt    = (bf16_t*)(ws + 2101248 + 2 * 8388608);
  bf16_t* vt    = (bf16_t*)(ws + 2101248 + 3 * 8388608);
  bf16_t* at    = (bf16_t*)(ws + 2101248 + 4 * 8388608);

  hipLaunchKernelGGL(cvt_bf16, dim3(768), dim3(256), 0, stream, qkvw, wqb, 1536 * 512);
  hipLaunchKernelGGL(cvt_bf16, dim3(256), dim3(256), 0, stream, projw, wpb, 512 * 512);
  hipLaunchKernelGGL(gn_stats, dim3(256), dim3(256), 0, stream, x, stats);
  hipLaunchKernelGGL(norm_t, dim3(16, 16, BATCH), dim3(256), 0, stream,
                     x, stats, gsc, gbi, xnT);
  hipLaunchKernelGGL(qkv_mfma, dim3(BATCH, 12, 8), dim3(256), 0, stream,
                     wqb, xnT, qkvb, qt, kt, vt);
  hipLaunchKernelGGL(attn_mfma, dim3(64, 16), dim3(256), 0, stream, qt, kt, vt, at);
  hipLaunchKernelGGL(proj_mfma, dim3(BATCH, 4, 8), dim3(256), 0, stream,
                     wpb, at, projb, x, out);
}

// Round 6
// 162.290 us; speedup vs baseline: 5.7627x; 1.0606x over previous
//
#include <hip/hip_runtime.h>
#include <math.h>

// (B,C,H,W)=(8,512,32,32), L=1024, 32 groups, 8 heads, ch=64
#define BATCH   8
#define CCH     512
#define LL      1024
#define NHEADS  8
#define CHD     64
#define EPSV    1e-5f
#define QSCALE  0.1803368801111204f   // 0.125 / ln(2): folded into q so S is in log2 units

typedef __bf16 bf16_t;
typedef bf16_t bf16x8 __attribute__((ext_vector_type(8)));
typedef bf16_t bf16x4 __attribute__((ext_vector_type(4)));
typedef float  f32x4  __attribute__((ext_vector_type(4)));

__device__ __forceinline__ bf16_t f2b(float f) {
  unsigned u = __float_as_uint(f);
  u += 0x7fff + ((u >> 16) & 1);               // RNE
  return __builtin_bit_cast(bf16_t, (unsigned short)(u >> 16));
}

__device__ __forceinline__ unsigned pack2(float lo, float hi) {
  unsigned a = (unsigned)__builtin_bit_cast(unsigned short, f2b(lo));
  unsigned b = (unsigned)__builtin_bit_cast(unsigned short, f2b(hi));
  return (b << 16) | a;
}

__device__ __forceinline__ void gload_lds16(const void* g, void* l) {
  __builtin_amdgcn_global_load_lds(
      (const __attribute__((address_space(1))) void*)g,
      (__attribute__((address_space(3))) void*)l, 16, 0, 0);
}

// ---------------------------------------------------------------------------
// K1: fused GroupNorm stats + normalize + affine + transpose -> xnT bf16.
// One block per (b,g): 16 ch x 1024 l cached in registers (single x read).
// Grid mapping puts the 4 g-quads sharing each 128-B output line on one XCD:
//   lin: xcd=lin&7, slot=lin>>3, b=slot&7, jj=slot>>3, g=xcd*4+jj.
// ---------------------------------------------------------------------------
__global__ __launch_bounds__(256) void gn_norm(const float* __restrict__ x,
                                               const float* __restrict__ gsc,
                                               const float* __restrict__ gbi,
                                               bf16_t* __restrict__ xnT) {
  int lin = blockIdx.x;
  int xcd = lin & 7, slot = lin >> 3;
  int b = slot & 7, jj = slot >> 3;
  int g = xcd * 4 + jj;
  const float4* x4 = (const float4*)(x + ((size_t)(b * 32 + g)) * 16 * LL);
  int tid = threadIdx.x;

  float s = 0.f, ss = 0.f;
  float4 v[16];                                 // v[it] = channel it, l = 4*tid..
#pragma unroll
  for (int it = 0; it < 16; ++it) {
    float4 f = x4[it * 256 + tid];
    v[it] = f;
    s += f.x + f.y + f.z + f.w;
    ss += f.x * f.x + f.y * f.y + f.z * f.z + f.w * f.w;
  }
#pragma unroll
  for (int m = 1; m < 64; m <<= 1) { s += __shfl_xor(s, m); ss += __shfl_xor(ss, m); }
  __shared__ float rs_[4], rss[4];
  int wv = tid >> 6, ln = tid & 63;
  if (ln == 0) { rs_[wv] = s; rss[wv] = ss; }
  __syncthreads();
  s  = rs_[0] + rs_[1] + rs_[2] + rs_[3];
  ss = rss[0] + rss[1] + rss[2] + rss[3];
  float mean = s * (1.f / 16384.f);
  float var  = ss * (1.f / 16384.f) - mean * mean;
  float rstd = rsqrtf(var + EPSV);

  float sc[16], bi[16];
#pragma unroll
  for (int it = 0; it < 16; ++it) {
    sc[it] = gsc[g * 16 + it] * rstd;
    bi[it] = gbi[g * 16 + it] - mean * sc[it];
  }

  // write transposed: xnT[b][l][g*16 .. g*16+15], 32 B per l, l = 4*tid+j
#pragma unroll
  for (int j = 0; j < 4; ++j) {
    unsigned w[8];
#pragma unroll
    for (int k = 0; k < 8; ++k) {
      float a0 = (j == 0 ? v[2 * k].x : j == 1 ? v[2 * k].y : j == 2 ? v[2 * k].z : v[2 * k].w);
      float a1 = (j == 0 ? v[2 * k + 1].x : j == 1 ? v[2 * k + 1].y : j == 2 ? v[2 * k + 1].z : v[2 * k + 1].w);
      w[k] = pack2(a0 * sc[2 * k] + bi[2 * k], a1 * sc[2 * k + 1] + bi[2 * k + 1]);
    }
    int l = tid * 4 + j;
    bf16_t* dst = xnT + ((size_t)b * LL + l) * CCH + g * 16;
    *(uint4*)dst = make_uint4(w[0], w[1], w[2], w[3]);
    *(uint4*)(dst + 8) = make_uint4(w[4], w[5], w[6], w[7]);
  }
}

// ---------------------------------------------------------------------------
// K3: fp32 -> bf16 weight convert
// ---------------------------------------------------------------------------
__global__ __launch_bounds__(256) void cvt_bf16(const float* __restrict__ src,
                                                bf16_t* __restrict__ dst, int n) {
  int i = (blockIdx.x * 256 + threadIdx.x) * 4;
  if (i < n) {
    float4 v = *(const float4*)(src + i);
    bf16x4 o = {f2b(v.x), f2b(v.y), f2b(v.z), f2b(v.w)};
    *(bf16x4*)(dst + i) = o;
  }
}

// ---------------------------------------------------------------------------
// K4: qkv GEMM (MFMA), m97-style LDS staging.  Grid (x=b, y=ot, z=lt) so
// linear%8 == b (XCD/L2 locality on xnT[b]).  128x128 block tile, BK=64,
// global_load_lds width 16 with XOR-granule swizzle on the global source.
// Epilogue: b64 packed stores; q scaled by QSCALE; v transposed+s-permuted.
// ---------------------------------------------------------------------------
__global__ __launch_bounds__(256) void qkv_mfma(const bf16_t* __restrict__ wq,
                                                const bf16_t* __restrict__ xnT,
                                                const float* __restrict__ qkvb,
                                                bf16_t* __restrict__ qt,
                                                bf16_t* __restrict__ kt,
                                                bf16_t* __restrict__ vt) {
  __shared__ bf16_t As[128 * 64];   // [row o][c], 128-B rows, granule-swizzled
  __shared__ bf16_t Bs[128 * 64];   // [row l][c]
  int tid = threadIdx.x;
  int wave = tid >> 6, lane = tid & 63;
  int lrow = lane & 15, quad = lane >> 4;
  int wm = wave >> 1, wn = wave & 1;
  int b = blockIdx.x;
  int oBase = blockIdx.y * 128, lBase = blockIdx.z * 128;
  int srow = lane >> 3;
  int sgOff = (((lane & 7) ^ srow) << 4);

  f32x4 acc[4][4] = {};
  for (int ktile = 0; ktile < 8; ++ktile) {
    int kB = ktile * 64;
    __syncthreads();
#pragma unroll
    for (int j = 0; j < 4; ++j) {
      int ci = wave * 4 + j;
      int R = ci * 8 + srow;
      gload_lds16((const char*)(wq + (size_t)(oBase + R) * CCH + kB) + sgOff,
                  (char*)As + ci * 1024);
      gload_lds16((const char*)(xnT + ((size_t)b * LL + lBase + R) * CCH + kB) + sgOff,
                  (char*)Bs + ci * 1024);
    }
    __syncthreads();
#pragma unroll
    for (int kk = 0; kk < 2; ++kk) {
      bf16x8 af[4], bfr[4];
#pragma unroll
      for (int m = 0; m < 4; ++m) {
        int r = wm * 64 + m * 16 + lrow;
        int g = (kk * 4 + quad) ^ (lrow & 7);
        af[m] = *(const bf16x8*)(As + r * 64 + g * 8);
      }
#pragma unroll
      for (int n = 0; n < 4; ++n) {
        int r = wn * 64 + n * 16 + lrow;
        int g = (kk * 4 + quad) ^ (lrow & 7);
        bfr[n] = *(const bf16x8*)(Bs + r * 64 + g * 8);
      }
#pragma unroll
      for (int m = 0; m < 4; ++m)
#pragma unroll
        for (int n = 0; n < 4; ++n)
          acc[m][n] = __builtin_amdgcn_mfma_f32_16x16x32_bf16(af[m], bfr[n], acc[m][n], 0, 0, 0);
    }
  }

  int oW = oBase + wm * 64;
  int lW = lBase + wn * 64;
  int sec = oW >> 9;
#pragma unroll
  for (int m = 0; m < 4; ++m) {
    int o4 = oW + m * 16 + quad * 4;
    float4 bb4 = *(const float4*)&qkvb[o4];
    int cc = o4 & 511;
    int head = cc >> 6, ch = cc & 63;
    int bh = b * NHEADS + head;
    if (sec == 0) {
#pragma unroll
      for (int n = 0; n < 4; ++n) {
        int l = lW + n * 16 + lrow;
        unsigned d0 = pack2((acc[m][n][0] + bb4.x) * QSCALE,
                            (acc[m][n][1] + bb4.y) * QSCALE);
        unsigned d1 = pack2((acc[m][n][2] + bb4.z) * QSCALE,
                            (acc[m][n][3] + bb4.w) * QSCALE);
        *(uint2*)(qt + ((size_t)bh * LL + l) * CHD + ch) = make_uint2(d0, d1);
      }
    } else if (sec == 1) {
#pragma unroll
      for (int n = 0; n < 4; ++n) {
        int l = lW + n * 16 + lrow;
        unsigned d0 = pack2(acc[m][n][0] + bb4.x, acc[m][n][1] + bb4.y);
        unsigned d1 = pack2(acc[m][n][2] + bb4.z, acc[m][n][3] + bb4.w);
        *(uint2*)(kt + ((size_t)bh * LL + l) * CHD + ch) = make_uint2(d0, d1);
      }
    } else {
      float bb[4] = {bb4.x, bb4.y, bb4.z, bb4.w};
#pragma unroll
      for (int i = 0; i < 4; ++i) {
        unsigned d0 = pack2(acc[m][0][i] + bb[i], acc[m][1][i] + bb[i]);
        unsigned d1 = pack2(acc[m][2][i] + bb[i], acc[m][3][i] + bb[i]);
        *(uint2*)(vt + ((size_t)bh * CHD + ch + i) * LL + lW + lrow * 4) =
            make_uint2(d0, d1);
      }
    }
  }
}

// ---------------------------------------------------------------------------
// K5: flash attention (MFMA), no-max softmax in log2 units.
// Block = (bh, 128 q-rows); each wave owns 32 q-rows (two 16-row subtiles h)
// so each K/V LDS fragment feeds 2x the MFMA work (DS-traffic per row halved).
// Grid (x=bh, y=t-tile) -> linear%8 == bh%8 (XCD locality).  K/V double-
// buffered LDS via global_load_lds w16 + XOR-granule swizzle; exp2-only
// softmax; row-sum via ones-MFMA; P through wave-private LDS.
// ---------------------------------------------------------------------------
__global__ __launch_bounds__(256) void attn_mfma(const bf16_t* __restrict__ qt,
                                                 const bf16_t* __restrict__ kt,
                                                 const bf16_t* __restrict__ vt,
                                                 bf16_t* __restrict__ at) {
  __shared__ bf16_t kbuf[2][64 * 64];
  __shared__ bf16_t vbuf[2][64 * 64];
  __shared__ bf16_t pb[8 * 16 * 72];            // per (wave,h) P tile, stride 72
  int tid = threadIdx.x, wave = tid >> 6, lane = tid & 63;
  int lrow = lane & 15, quad = lane >> 4;
  int bh = blockIdx.x;
  int tW = blockIdx.y * 128 + wave * 32;
  const bf16_t* qb = qt + (size_t)bh * LL * CHD;
  const bf16_t* kb = kt + (size_t)bh * LL * CHD;
  const bf16_t* vb = vt + (size_t)bh * CHD * LL;

  int srow = lane >> 3;
  int sgb = (((lane & 7) ^ srow) << 4);

  bf16x8 qf[2][2];
#pragma unroll
  for (int h = 0; h < 2; ++h) {
    const bf16_t* qp = qb + (size_t)(tW + h * 16 + lrow) * CHD + quad * 8;
    qf[h][0] = *(const bf16x8*)qp;
    qf[h][1] = *(const bf16x8*)(qp + 32);
  }

  bf16x8 ones;
#pragma unroll
  for (int j = 0; j < 8; ++j) ones[j] = (bf16_t)1.0f;

  f32x4 Oa[2][4] = {};
  f32x4 Os[2] = {};

#pragma unroll
  for (int j = 0; j < 2; ++j) {
    int c = wave * 2 + j;
    int R = c * 8 + srow;
    gload_lds16((const char*)(kb + (size_t)R * CHD) + sgb, (char*)&kbuf[0][0] + c * 1024);
    gload_lds16((const char*)(vb + (size_t)R * LL) + sgb, (char*)&vbuf[0][0] + c * 1024);
  }
  __syncthreads();

  int swz0 = (quad ^ (lrow & 7)) * 8;
  int swz1 = ((quad + 4) ^ (lrow & 7)) * 8;

  for (int st = 0; st < 16; ++st) {
    int cur = st & 1;
    if (st < 15) {
      int sBn = (st + 1) * 64;
#pragma unroll
      for (int j = 0; j < 2; ++j) {
        int c = wave * 2 + j;
        int R = c * 8 + srow;
        gload_lds16((const char*)(kb + (size_t)(sBn + R) * CHD) + sgb,
                    (char*)&kbuf[cur ^ 1][0] + c * 1024);
        gload_lds16((const char*)(vb + (size_t)R * LL + sBn) + sgb,
                    (char*)&vbuf[cur ^ 1][0] + c * 1024);
      }
    }
    const bf16_t* kbase = &kbuf[cur][0];
    const bf16_t* vbase = &vbuf[cur][0];

    f32x4 S[2][4];
#pragma unroll
    for (int ss = 0; ss < 4; ++ss) {
      int s = ss * 16 + lrow;
      bf16x8 k0 = *(const bf16x8*)(kbase + s * 64 + swz0);
      bf16x8 k1 = *(const bf16x8*)(kbase + s * 64 + swz1);
#pragma unroll
      for (int h = 0; h < 2; ++h) {
        f32x4 z = {0.f, 0.f, 0.f, 0.f};
        z = __builtin_amdgcn_mfma_f32_16x16x32_bf16(qf[h][0], k0, z, 0, 0, 0);
        S[h][ss] = __builtin_amdgcn_mfma_f32_16x16x32_bf16(qf[h][1], k1, z, 0, 0, 0);
      }
    }

#pragma unroll
    for (int h = 0; h < 2; ++h) {
      bf16_t* pw = pb + (wave * 2 + h) * (16 * 72);
      float p[4][4];
#pragma unroll
      for (int ss = 0; ss < 4; ++ss)
#pragma unroll
        for (int i = 0; i < 4; ++i)
          p[ss][i] = __builtin_amdgcn_exp2f(S[h][ss][i]);
#pragma unroll
      for (int i = 0; i < 4; ++i) {
        unsigned d0 = __builtin_amdgcn_perm(__float_as_uint(p[1][i]),
                                            __float_as_uint(p[0][i]), 0x07060302u);
        unsigned d1 = __builtin_amdgcn_perm(__float_as_uint(p[3][i]),
                                            __float_as_uint(p[2][i]), 0x07060302u);
        uint2* dst = (uint2*)(pw + (quad * 4 + i) * 72 + lrow * 4);
        *dst = make_uint2(d0, d1);
      }
    }
    asm volatile("s_waitcnt lgkmcnt(0)" ::: "memory");   // wave-private P

    bf16x8 pf[2][2];
#pragma unroll
    for (int h = 0; h < 2; ++h) {
      const bf16_t* pw = pb + (wave * 2 + h) * (16 * 72);
      pf[h][0] = *(const bf16x8*)(pw + lrow * 72 + quad * 8);
      pf[h][1] = *(const bf16x8*)(pw + lrow * 72 + 32 + quad * 8);
    }

#pragma unroll
    for (int n = 0; n < 4; ++n) {
      int r = (n * 16 + lrow) * 64;
      bf16x8 v0 = *(const bf16x8*)(vbase + r + swz0);
      bf16x8 v1 = *(const bf16x8*)(vbase + r + swz1);
#pragma unroll
      for (int h = 0; h < 2; ++h) {
        Oa[h][n] = __builtin_amdgcn_mfma_f32_16x16x32_bf16(pf[h][0], v0, Oa[h][n], 0, 0, 0);
        Oa[h][n] = __builtin_amdgcn_mfma_f32_16x16x32_bf16(pf[h][1], v1, Oa[h][n], 0, 0, 0);
      }
    }
#pragma unroll
    for (int h = 0; h < 2; ++h) {
      Os[h] = __builtin_amdgcn_mfma_f32_16x16x32_bf16(pf[h][0], ones, Os[h], 0, 0, 0);
      Os[h] = __builtin_amdgcn_mfma_f32_16x16x32_bf16(pf[h][1], ones, Os[h], 0, 0, 0);
    }

    __syncthreads();
  }

  bf16_t* ab = at + (size_t)bh * LL * CHD;
#pragma unroll
  for (int h = 0; h < 2; ++h) {
    float inv[4];
#pragma unroll
    for (int i = 0; i < 4; ++i) inv[i] = 1.f / Os[h][i];
#pragma unroll
    for (int n = 0; n < 4; ++n)
#pragma unroll
      for (int i = 0; i < 4; ++i)
        ab[(size_t)(tW + h * 16 + quad * 4 + i) * CHD + n * 16 + lrow] =
            f2b(Oa[h][n][i] * inv[i]);
  }
}

// ---------------------------------------------------------------------------
// K6: proj GEMM (MFMA) + bias + fp32 residual, LDS-staged like K4.
// BK=64 == one head of at.  Grid (x=b, y=ot, z=lt), linear%8 == b.
// ---------------------------------------------------------------------------
__global__ __launch_bounds__(256) void proj_mfma(const bf16_t* __restrict__ wp,
                                                 const bf16_t* __restrict__ at,
                                                 const float* __restrict__ projb,
                                                 const float* __restrict__ x,
                                                 float* __restrict__ out) {
  __shared__ bf16_t As[128 * 64];
  __shared__ bf16_t Bs[128 * 64];
  int tid = threadIdx.x;
  int wave = tid >> 6, lane = tid & 63;
  int lrow = lane & 15, quad = lane >> 4;
  int wm = wave >> 1, wn = wave & 1;
  int b = blockIdx.x;
  int oBase = blockIdx.y * 128, lBase = blockIdx.z * 128;
  int srow = lane >> 3;
  int sgOff = (((lane & 7) ^ srow) << 4);

  f32x4 acc[4][4] = {};
  for (int ktile = 0; ktile < 8; ++ktile) {     // head = ktile
    int kB = ktile * 64;
    __syncthreads();
#pragma unroll
    for (int j = 0; j < 4; ++j) {
      int ci = wave * 4 + j;
      int R = ci * 8 + srow;
      gload_lds16((const char*)(wp + (size_t)(oBase + R) * CCH + kB) + sgOff,
                  (char*)As + ci * 1024);
      gload_lds16((const char*)(at + ((size_t)(b * NHEADS + ktile) * LL + lBase + R) * CHD) + sgOff,
                  (char*)Bs + ci * 1024);
    }
    __syncthreads();
#pragma unroll
    for (int kk = 0; kk < 2; ++kk) {
      bf16x8 af[4], bfr[4];
#pragma unroll
      for (int m = 0; m < 4; ++m) {
        int r = wm * 64 + m * 16 + lrow;
        int g = (kk * 4 + quad) ^ (lrow & 7);
        af[m] = *(const bf16x8*)(As + r * 64 + g * 8);
      }
#pragma unroll
      for (int n = 0; n < 4; ++n) {
        int r = wn * 64 + n * 16 + lrow;
        int g = (kk * 4 + quad) ^ (lrow & 7);
        bfr[n] = *(const bf16x8*)(Bs + r * 64 + g * 8);
      }
#pragma unroll
      for (int m = 0; m < 4; ++m)
#pragma unroll
        for (int n = 0; n < 4; ++n)
          acc[m][n] = __builtin_amdgcn_mfma_f32_16x16x32_bf16(af[m], bfr[n], acc[m][n], 0, 0, 0);
    }
  }

  int oW = oBase + wm * 64;
  int lW = lBase + wn * 64;
#pragma unroll
  for (int m = 0; m < 4; ++m) {
#pragma unroll
    for (int i = 0; i < 4; ++i) {
      int o = oW + m * 16 + quad * 4 + i;
      float bb = projb[o];
#pragma unroll
      for (int n = 0; n < 4; ++n) {
        int l = lW + n * 16 + lrow;
        size_t off = ((size_t)(b * CCH + o)) * LL + l;
        out[off] = acc[m][n][i] + bb + x[off];
      }
    }
  }
}

// ---------------------------------------------------------------------------
extern "C" void kernel_launch(void* const* d_in, const int* in_sizes, int n_in,
                              void* d_out, int out_size, void* d_ws, size_t ws_size,
                              hipStream_t stream) {
  const float* x     = (const float*)d_in[0];
  const float* gsc   = (const float*)d_in[1];
  const float* gbi   = (const float*)d_in[2];
  const float* qkvw  = (const float*)d_in[3];
  const float* qkvb  = (const float*)d_in[4];
  const float* projw = (const float*)d_in[5];
  const float* projb = (const float*)d_in[6];
  float* out = (float*)d_out;

  char* ws = (char*)d_ws;
  bf16_t* wqb   = (bf16_t*)(ws + 4096);
  bf16_t* wpb   = (bf16_t*)(ws + 4096 + 1572864);
  bf16_t* xnT   = (bf16_t*)(ws + 2101248);
  bf16_t* qt    = (bf16_t*)(ws + 2101248 + 8388608);
  bf16_t* kt    = (bf16_t*)(ws + 2101248 + 2 * 8388608);
  bf16_t* vt    = (bf16_t*)(ws + 2101248 + 3 * 8388608);
  bf16_t* at    = (bf16_t*)(ws + 2101248 + 4 * 8388608);

  hipLaunchKernelGGL(cvt_bf16, dim3(768), dim3(256), 0, stream, qkvw, wqb, 1536 * 512);
  hipLaunchKernelGGL(cvt_bf16, dim3(256), dim3(256), 0, stream, projw, wpb, 512 * 512);
  hipLaunchKernelGGL(gn_norm, dim3(256), dim3(256), 0, stream, x, gsc, gbi, xnT);
  hipLaunchKernelGGL(qkv_mfma, dim3(BATCH, 12, 8), dim3(256), 0, stream,
                     wqb, xnT, qkvb, qt, kt, vt);
  hipLaunchKernelGGL(attn_mfma, dim3(64, 8), dim3(256), 0, stream, qt, kt, vt, at);
  hipLaunchKernelGGL(proj_mfma, dim3(BATCH, 4, 8), dim3(256), 0, stream,
                     wpb, at, projb, x, out);
}